// Round 1
// baseline (673.595 us; speedup 1.0000x reference)
//
#include <hip/hip_runtime.h>
#include <math.h>

#define TM 64
#define TN 128
#define KC 32

// ---------------------------------------------------------------------------
// Tiled fp32 GEMM: out[M x NC] = act(A[M x KD] @ W[KD x NC] + bias)
// MODE 0: none, 1: relu, 2: +res then row LayerNorm (requires NC == 128)
// Block: 256 threads, tile 64 rows x 128 cols, each thread 4x8 outputs.
// ---------------------------------------------------------------------------
template<int KD, int NC, int MODE>
__global__ __launch_bounds__(256)
void gemm_kernel(const float* __restrict__ A,
                 const float* __restrict__ W,
                 const float* __restrict__ bias,
                 const float* __restrict__ res,
                 const float* __restrict__ lng,
                 const float* __restrict__ lnb,
                 float* __restrict__ out, int M)
{
    __shared__ float As[TM][KC + 1];   // +1 pad breaks bank aliasing on column reads
    __shared__ float Ws[KC][TN];

    const int tid  = threadIdx.x;
    const int trow = tid >> 4;         // 0..15  (4 rows each)
    const int tcol = tid & 15;         // 0..15  (8 cols each)
    const int rowBase = blockIdx.x * TM;
    const int colBase = blockIdx.y * TN;

    float acc[4][8];
#pragma unroll
    for (int i = 0; i < 4; ++i)
#pragma unroll
        for (int j = 0; j < 8; ++j) acc[i][j] = 0.f;

    for (int k0 = 0; k0 < KD; k0 += KC) {
        // stage A tile: 64 x 32 floats = 512 float4, 2 per thread
#pragma unroll
        for (int t = 0; t < 2; ++t) {
            int f = tid + t * 256;
            int r = f >> 3, q = f & 7;
            int row = rowBase + r;
            float4 av = make_float4(0.f, 0.f, 0.f, 0.f);
            if (row < M) av = *(const float4*)(A + (size_t)row * KD + k0 + q * 4);
            As[r][q * 4 + 0] = av.x;
            As[r][q * 4 + 1] = av.y;
            As[r][q * 4 + 2] = av.z;
            As[r][q * 4 + 3] = av.w;
        }
        // stage W tile: 32 x 128 floats = 1024 float4, 4 per thread
#pragma unroll
        for (int t = 0; t < 4; ++t) {
            int f = tid + t * 256;
            int kk = f >> 5, q = f & 31;
            float4 wv = *(const float4*)(W + (size_t)(k0 + kk) * NC + colBase + q * 4);
            *(float4*)(&Ws[kk][q * 4]) = wv;
        }
        __syncthreads();
#pragma unroll
        for (int kk = 0; kk < KC; ++kk) {
            float a[4], b[8];
#pragma unroll
            for (int i = 0; i < 4; ++i) a[i] = As[trow * 4 + i][kk];
#pragma unroll
            for (int j = 0; j < 8; ++j) b[j] = Ws[kk][tcol * 8 + j];
#pragma unroll
            for (int i = 0; i < 4; ++i)
#pragma unroll
                for (int j = 0; j < 8; ++j)
                    acc[i][j] = fmaf(a[i], b[j], acc[i][j]);
        }
        __syncthreads();
    }

    const int col0 = colBase + tcol * 8;
    float bb[8];
    *(float4*)&bb[0] = *(const float4*)(bias + col0);
    *(float4*)&bb[4] = *(const float4*)(bias + col0 + 4);

    if (MODE == 2) {
        float gg[8], be[8];
        *(float4*)&gg[0] = *(const float4*)(lng + col0);
        *(float4*)&gg[4] = *(const float4*)(lng + col0 + 4);
        *(float4*)&be[0] = *(const float4*)(lnb + col0);
        *(float4*)&be[4] = *(const float4*)(lnb + col0 + 4);
#pragma unroll
        for (int i = 0; i < 4; ++i) {
            int row = rowBase + trow * 4 + i;
            if (row >= M) continue;     // uniform across the 16-lane shfl group
            float rr[8];
            *(float4*)&rr[0] = *(const float4*)(res + (size_t)row * 128 + col0);
            *(float4*)&rr[4] = *(const float4*)(res + (size_t)row * 128 + col0 + 4);
            float v[8], s = 0.f, ss = 0.f;
#pragma unroll
            for (int j = 0; j < 8; ++j) {
                v[j] = acc[i][j] + bb[j] + rr[j];
                s += v[j];
                ss += v[j] * v[j];
            }
#pragma unroll
            for (int off = 1; off < 16; off <<= 1) {
                s  += __shfl_xor(s,  off, 64);
                ss += __shfl_xor(ss, off, 64);
            }
            float mean = s * (1.f / 128.f);
            float var  = ss * (1.f / 128.f) - mean * mean;
            float rstd = rsqrtf(var + 1e-5f);
            float o[8];
#pragma unroll
            for (int j = 0; j < 8; ++j)
                o[j] = (v[j] - mean) * rstd * gg[j] + be[j];
            *(float4*)(out + (size_t)row * 128 + col0)     = *(float4*)&o[0];
            *(float4*)(out + (size_t)row * 128 + col0 + 4) = *(float4*)&o[4];
        }
    } else {
#pragma unroll
        for (int i = 0; i < 4; ++i) {
            int row = rowBase + trow * 4 + i;
            if (row >= M) continue;
            float v[8];
#pragma unroll
            for (int j = 0; j < 8; ++j) {
                v[j] = acc[i][j] + bb[j];
                if (MODE == 1) v[j] = fmaxf(v[j], 0.f);
            }
            *(float4*)(out + (size_t)row * NC + col0)     = *(float4*)&v[0];
            *(float4*)(out + (size_t)row * NC + col0 + 4) = *(float4*)&v[4];
        }
    }
}

// ---------------------------------------------------------------------------
// CSR build: histogram, scan, scatter
// ---------------------------------------------------------------------------
__global__ void deg_kernel(const int* __restrict__ tgt, int* __restrict__ deg, int E)
{
    int i = blockIdx.x * blockDim.x + threadIdx.x;
    if (i < E) atomicAdd(&deg[tgt[i]], 1);
}

__global__ __launch_bounds__(1024)
void scan_kernel(const int* __restrict__ deg, int* __restrict__ row_ptr, int n)
{
    __shared__ int sh[1024];
    __shared__ int carry;
    const int tid = threadIdx.x;
    if (tid == 0) carry = 0;
    __syncthreads();
    for (int base = 0; base < n; base += 1024) {
        int v = (base + tid < n) ? deg[base + tid] : 0;
        sh[tid] = v;
        __syncthreads();
        for (int off = 1; off < 1024; off <<= 1) {
            int y = (tid >= off) ? sh[tid - off] : 0;
            __syncthreads();
            sh[tid] += y;
            __syncthreads();
        }
        int incl = sh[tid];
        if (base + tid < n) row_ptr[base + tid] = carry + incl - v;
        __syncthreads();
        if (tid == 0) carry += sh[1023];
        __syncthreads();
    }
    if (tid == 0) row_ptr[n] = carry;
}

__global__ void scatter_kernel(const int* __restrict__ src, const int* __restrict__ tgt,
                               const int* __restrict__ row_ptr, int* __restrict__ cursor,
                               int* __restrict__ ssrc, int E)
{
    int i = blockIdx.x * blockDim.x + threadIdx.x;
    if (i < E) {
        int t = tgt[i];
        int pos = row_ptr[t] + atomicAdd(&cursor[t], 1);
        ssrc[pos] = src[i];
    }
}

// ---------------------------------------------------------------------------
// Per-node attention: one wave per target node, online softmax in registers.
// Lane l holds feature dims 2l, 2l+1; head = lane/8 (16 dims per head = 8 lanes).
// ---------------------------------------------------------------------------
__global__ __launch_bounds__(256)
void attn_kernel(const float* __restrict__ Q, const float* __restrict__ K,
                 const float* __restrict__ V, const int* __restrict__ row_ptr,
                 const int* __restrict__ ssrc, float* __restrict__ agg, int n)
{
    int wid  = (blockIdx.x * blockDim.x + threadIdx.x) >> 6;
    int lane = threadIdx.x & 63;
    if (wid >= n) return;

    const float2 q = *(const float2*)(Q + (size_t)wid * 128 + lane * 2);
    int e0 = row_ptr[wid], e1 = row_ptr[wid + 1];

    float m = -INFINITY, lsum = 0.f, a0 = 0.f, a1 = 0.f;
    for (int e = e0; e < e1; ++e) {
        int s = ssrc[e];
        const float2 kv = *(const float2*)(K + (size_t)s * 128 + lane * 2);
        float p = q.x * kv.x + q.y * kv.y;
        p += __shfl_xor(p, 1, 64);
        p += __shfl_xor(p, 2, 64);
        p += __shfl_xor(p, 4, 64);
        float sc = p * 0.25f;                 // 1/sqrt(16)
        float mn = fmaxf(m, sc);
        float scale = __expf(m - mn);         // exp(-inf)=0 on first edge
        float w = __expf(sc - mn);
        const float2 vv = *(const float2*)(V + (size_t)s * 128 + lane * 2);
        lsum = lsum * scale + w;
        a0 = a0 * scale + w * vv.x;
        a1 = a1 * scale + w * vv.y;
        m = mn;
    }
    float inv = 1.f / (lsum + 1e-16f);
    *(float2*)(agg + (size_t)wid * 128 + lane * 2) = make_float2(a0 * inv, a1 * inv);
}

// ---------------------------------------------------------------------------
extern "C" void kernel_launch(void* const* d_in, const int* in_sizes, int n_in,
                              void* d_out, int out_size, void* d_ws, size_t ws_size,
                              hipStream_t stream)
{
    const float* x    = (const float*)d_in[0];
    const float* Wq   = (const float*)d_in[1];
    const float* bq   = (const float*)d_in[2];
    const float* Wk   = (const float*)d_in[3];
    const float* bk   = (const float*)d_in[4];
    const float* Wv   = (const float*)d_in[5];
    const float* bv   = (const float*)d_in[6];
    const float* Wo   = (const float*)d_in[7];
    const float* bo   = (const float*)d_in[8];
    const float* ln1g = (const float*)d_in[9];
    const float* ln1b = (const float*)d_in[10];
    const float* W1   = (const float*)d_in[11];
    const float* b1   = (const float*)d_in[12];
    const float* W2   = (const float*)d_in[13];
    const float* b2   = (const float*)d_in[14];
    const float* ln2g = (const float*)d_in[15];
    const float* ln2b = (const float*)d_in[16];
    const int*   eidx = (const int*)d_in[17];

    const int N_ = in_sizes[0] / 128;
    const int E_ = in_sizes[17] / 2;
    const int* srcE = eidx;
    const int* tgtE = eidx + E_;
    float* out = (float*)d_out;

    float* ws = (float*)d_ws;
    const size_t NF = (size_t)N_ * 128;
    float* Qb   = ws;
    float* Kb   = Qb + NF;
    float* Vb   = Kb + NF;
    float* aggb = Vb + NF;
    float* hb   = aggb + NF;
    float* tb   = ws;                 // reuses Q..agg after attention (N x 512)
    int* ib   = (int*)(hb + NF);
    int* deg  = ib;
    int* rowp = deg + N_;
    int* cur  = rowp + N_ + 1;
    int* ssrc = cur + N_;

    hipMemsetAsync(deg, 0, sizeof(int) * N_, stream);
    hipMemsetAsync(cur, 0, sizeof(int) * N_, stream);

    dim3 blk(256);
    int gm = (N_ + TM - 1) / TM;

    gemm_kernel<128, 128, 0><<<dim3(gm, 1), blk, 0, stream>>>(x, Wq, bq, nullptr, nullptr, nullptr, Qb, N_);
    gemm_kernel<128, 128, 0><<<dim3(gm, 1), blk, 0, stream>>>(x, Wk, bk, nullptr, nullptr, nullptr, Kb, N_);
    gemm_kernel<128, 128, 0><<<dim3(gm, 1), blk, 0, stream>>>(x, Wv, bv, nullptr, nullptr, nullptr, Vb, N_);

    deg_kernel<<<(E_ + 255) / 256, 256, 0, stream>>>(tgtE, deg, E_);
    scan_kernel<<<1, 1024, 0, stream>>>(deg, rowp, N_);
    scatter_kernel<<<(E_ + 255) / 256, 256, 0, stream>>>(srcE, tgtE, rowp, cur, ssrc, E_);

    attn_kernel<<<(N_ * 64 + 255) / 256, 256, 0, stream>>>(Qb, Kb, Vb, rowp, ssrc, aggb, N_);

    gemm_kernel<128, 128, 2><<<dim3(gm, 1), blk, 0, stream>>>(aggb, Wo, bo, x, ln1g, ln1b, hb, N_);
    gemm_kernel<128, 512, 1><<<dim3(gm, 4), blk, 0, stream>>>(hb, W1, b1, nullptr, nullptr, nullptr, tb, N_);
    gemm_kernel<512, 128, 2><<<dim3(gm, 1), blk, 0, stream>>>(tb, W2, b2, hb, ln2g, ln2b, out, N_);
}

// Round 2
// 342.590 us; speedup vs baseline: 1.9662x; 1.9662x over previous
//
#include <hip/hip_runtime.h>
#include <math.h>

typedef __attribute__((ext_vector_type(8))) short bf16x8;
typedef __attribute__((ext_vector_type(4))) float f32x4;

__device__ __forceinline__ unsigned short f2b(float f) {
    unsigned int u = __float_as_uint(f);
    unsigned int r = (u + 0x7fffu + ((u >> 16) & 1u)) >> 16;   // RTNE
    return (unsigned short)r;
}
__device__ __forceinline__ float blo(unsigned int w) { return __uint_as_float(w << 16); }
__device__ __forceinline__ float bhi(unsigned int w) { return __uint_as_float(w & 0xffff0000u); }

__device__ __forceinline__ void gload_lds16(const void* g, void* lds) {
    __builtin_amdgcn_global_load_lds(
        (const __attribute__((address_space(1))) unsigned int*)g,
        (__attribute__((address_space(3))) unsigned int*)lds, 16, 0, 0);
}

// ---------------------------------------------------------------------------
// bf16 MFMA GEMM: out[M x NC] = act(A[Mpad x K] @ W[K x NC] + bias)
// BT is W transposed, row-major [NC x K] bf16. Tile 128x128, BK=32, 4 waves.
// ---------------------------------------------------------------------------
template<int K, int RELU, int OUT_BF16>
__global__ __launch_bounds__(256)
void mfma_gemm(const unsigned short* __restrict__ A,
               const unsigned short* __restrict__ BT,
               const float* __restrict__ bias,
               void* __restrict__ outv, int M, int NC)
{
    __shared__ unsigned short As[128 * 32];
    __shared__ unsigned short Bs[128 * 32];
    const int tid  = threadIdx.x;
    const int lane = tid & 63;
    const int wid  = tid >> 6;
    const int wr = wid >> 1, wc = wid & 1;
    const int rowBase = blockIdx.x * 128;
    const int colBase = blockIdx.y * 128;

    f32x4 acc[4][4];
#pragma unroll
    for (int i = 0; i < 4; ++i)
#pragma unroll
        for (int j = 0; j < 4; ++j) acc[i][j] = (f32x4)0.f;

    const int f0 = tid, f1 = tid + 256;
    const int r0 = f0 >> 2, kc0 = (f0 & 3) * 8;
    const int r1 = f1 >> 2, kc1 = (f1 & 3) * 8;

#pragma unroll
    for (int k0 = 0; k0 < K; k0 += 32) {
        gload_lds16(A + (size_t)(rowBase + r0) * K + k0 + kc0, &As[f0 * 8]);
        gload_lds16(A + (size_t)(rowBase + r1) * K + k0 + kc1, &As[f1 * 8]);
        gload_lds16(BT + (size_t)(colBase + r0) * K + k0 + kc0, &Bs[f0 * 8]);
        gload_lds16(BT + (size_t)(colBase + r1) * K + k0 + kc1, &Bs[f1 * 8]);
        __syncthreads();

        bf16x8 a[4], b[4];
        const int kh = (lane >> 4) * 8;
        const int rl = lane & 15;
#pragma unroll
        for (int mi = 0; mi < 4; ++mi)
            a[mi] = *(const bf16x8*)&As[(wr * 64 + mi * 16 + rl) * 32 + kh];
#pragma unroll
        for (int ni = 0; ni < 4; ++ni)
            b[ni] = *(const bf16x8*)&Bs[(wc * 64 + ni * 16 + rl) * 32 + kh];
#pragma unroll
        for (int mi = 0; mi < 4; ++mi)
#pragma unroll
            for (int ni = 0; ni < 4; ++ni)
                acc[mi][ni] = __builtin_amdgcn_mfma_f32_16x16x32_bf16(a[mi], b[ni], acc[mi][ni], 0, 0, 0);
        __syncthreads();
    }

#pragma unroll
    for (int ni = 0; ni < 4; ++ni) {
        const int col = colBase + wc * 64 + ni * 16 + (lane & 15);
        const float bv = bias[col];
#pragma unroll
        for (int mi = 0; mi < 4; ++mi) {
            const int rowb = rowBase + wr * 64 + mi * 16 + (lane >> 4) * 4;
#pragma unroll
            for (int r = 0; r < 4; ++r) {
                const int row = rowb + r;
                if (row >= M) continue;
                float v = acc[mi][ni][r] + bv;
                if (RELU) v = fmaxf(v, 0.f);
                if (OUT_BF16)
                    ((unsigned short*)outv)[(size_t)row * NC + col] = f2b(v);
                else
                    ((float*)outv)[(size_t)row * NC + col] = v;
            }
        }
    }
}

// ---------------------------------------------------------------------------
// casts
// ---------------------------------------------------------------------------
__global__ void cast_x(const float* __restrict__ x, unsigned short* __restrict__ xb,
                       int n, int npad)
{
    size_t i = ((size_t)blockIdx.x * blockDim.x + threadIdx.x) * 4;
    if (i >= (size_t)npad * 128) return;
    float4 v = make_float4(0.f, 0.f, 0.f, 0.f);
    if (i < (size_t)n * 128) v = *(const float4*)(x + i);
    ushort4 o;
    o.x = f2b(v.x); o.y = f2b(v.y); o.z = f2b(v.z); o.w = f2b(v.w);
    *(ushort4*)(xb + i) = o;
}

__global__ void cast_w(const float* __restrict__ Wq, const float* __restrict__ Wk,
                       const float* __restrict__ Wv, const float* __restrict__ Wo,
                       const float* __restrict__ W1, const float* __restrict__ W2,
                       const float* __restrict__ bq, const float* __restrict__ bk,
                       const float* __restrict__ bv,
                       unsigned short* __restrict__ WcatT, unsigned short* __restrict__ WoT,
                       unsigned short* __restrict__ W1T, unsigned short* __restrict__ W2T,
                       float* __restrict__ bqkv)
{
    int i = blockIdx.x * 256 + threadIdx.x;
    if (i < 49152) {                      // WcatT[384][128] = [Wq|Wk|Wv]^T
        int j = i >> 7, k = i & 127;
        const float* W = (j < 128) ? Wq : ((j < 256) ? Wk : Wv);
        WcatT[i] = f2b(W[k * 128 + (j & 127)]);
    } else if (i < 65536) {               // WoT[128][128]
        int t = i - 49152; int j = t >> 7, k = t & 127;
        WoT[t] = f2b(Wo[k * 128 + j]);
    } else if (i < 131072) {              // W1T[512][128], W1 is [128][512]
        int t = i - 65536; int j = t >> 7, k = t & 127;
        W1T[t] = f2b(W1[k * 512 + j]);
    } else if (i < 196608) {              // W2T[128][512], W2 is [512][128]
        int t = i - 131072; int j = t >> 9, k = t & 511;
        W2T[t] = f2b(W2[k * 128 + j]);
    }
    if (i < 384) bqkv[i] = (i < 128) ? bq[i] : ((i < 256) ? bk[i - 128] : bv[i - 256]);
}

// ---------------------------------------------------------------------------
// CSR build: histogram, 3-phase scan, scatter
// ---------------------------------------------------------------------------
__global__ void deg_kernel(const int* __restrict__ tgt, int* __restrict__ deg, int E)
{
    int i = blockIdx.x * blockDim.x + threadIdx.x;
    if (i < E) atomicAdd(&deg[tgt[i]], 1);
}

__global__ __launch_bounds__(1024)
void scan1(const int* __restrict__ deg, int* __restrict__ scn, int* __restrict__ bsum, int n)
{
    __shared__ int sh[1024];
    int gid = blockIdx.x * 1024 + threadIdx.x;
    int v = (gid < n) ? deg[gid] : 0;
    sh[threadIdx.x] = v;
    __syncthreads();
    for (int off = 1; off < 1024; off <<= 1) {
        int y = (threadIdx.x >= off) ? sh[threadIdx.x - off] : 0;
        __syncthreads();
        sh[threadIdx.x] += y;
        __syncthreads();
    }
    if (gid < n) scn[gid] = sh[threadIdx.x];
    if (threadIdx.x == 1023) bsum[blockIdx.x] = sh[1023];
}

__global__ void scan2(int* __restrict__ bsum, int nb)
{
    if (threadIdx.x == 0) {
        int acc = 0;
        for (int i = 0; i < nb; ++i) { int t = bsum[i]; bsum[i] = acc; acc += t; }
    }
}

__global__ void scan3(const int* __restrict__ scn, const int* __restrict__ deg,
                      const int* __restrict__ bsum, int* __restrict__ rowp, int n, int E)
{
    int gid = blockIdx.x * blockDim.x + threadIdx.x;
    if (gid < n) rowp[gid] = bsum[gid >> 10] + scn[gid] - deg[gid];
    if (gid == n) rowp[n] = E;
}

__global__ void scatter_kernel(const int* __restrict__ src, const int* __restrict__ tgt,
                               const int* __restrict__ rowp, int* __restrict__ cursor,
                               int* __restrict__ ssrc, int E)
{
    int i = blockIdx.x * blockDim.x + threadIdx.x;
    if (i < E) {
        int t = tgt[i];
        int pos = rowp[t] + atomicAdd(&cursor[t], 1);
        ssrc[pos] = src[i];
    }
}

// ---------------------------------------------------------------------------
// Attention: wave per target, online softmax, bf16 qkv gathers.
// qkv layout [npad][384]: Q dims 0..127, K 128..255, V 256..383.
// ---------------------------------------------------------------------------
__global__ __launch_bounds__(256)
void attn_kernel(const unsigned short* __restrict__ qkv, const int* __restrict__ rowp,
                 const int* __restrict__ ssrc, unsigned short* __restrict__ agg,
                 int n, int npad)
{
    int wid  = (blockIdx.x * blockDim.x + threadIdx.x) >> 6;
    int lane = threadIdx.x & 63;
    if (wid >= npad) return;
    if (wid >= n) { *(unsigned int*)(agg + (size_t)wid * 128 + lane * 2) = 0u; return; }

    unsigned int qw = *(const unsigned int*)(qkv + (size_t)wid * 384 + lane * 2);
    const float q0 = blo(qw), q1 = bhi(qw);
    int e0 = rowp[wid], e1 = rowp[wid + 1];

    float m = -INFINITY, l = 0.f, a0 = 0.f, a1 = 0.f;
    for (int e = e0; e < e1; ++e) {
        int s = ssrc[e];
        const unsigned short* kvp = qkv + (size_t)s * 384 + 128 + lane * 2;
        unsigned int kw = *(const unsigned int*)kvp;
        float p = q0 * blo(kw) + q1 * bhi(kw);
        p += __shfl_xor(p, 1, 64);
        p += __shfl_xor(p, 2, 64);
        p += __shfl_xor(p, 4, 64);
        float sc = p * 0.25f;                 // 1/sqrt(16)
        float mn = fmaxf(m, sc);
        float scale = __expf(m - mn);
        float w = __expf(sc - mn);
        unsigned int vw = *(const unsigned int*)(kvp + 128);
        l  = l * scale + w;
        a0 = a0 * scale + w * blo(vw);
        a1 = a1 * scale + w * bhi(vw);
        m = mn;
    }
    float inv = 1.f / (l + 1e-16f);
    unsigned int o = (unsigned int)f2b(a0 * inv) | ((unsigned int)f2b(a1 * inv) << 16);
    *(unsigned int*)(agg + (size_t)wid * 128 + lane * 2) = o;
}

// ---------------------------------------------------------------------------
// LayerNorm kernels, wave per row (64 lanes x 2 dims)
// ---------------------------------------------------------------------------
__global__ __launch_bounds__(256)
void ln1_kernel(const float* __restrict__ x, const float* __restrict__ o,
                const float* __restrict__ g, const float* __restrict__ b,
                unsigned short* __restrict__ h, int n, int npad)
{
    int wid  = (blockIdx.x * blockDim.x + threadIdx.x) >> 6;
    int lane = threadIdx.x & 63;
    if (wid >= npad) return;
    if (wid >= n) { *(unsigned int*)(h + (size_t)wid * 128 + lane * 2) = 0u; return; }
    float2 xv = *(const float2*)(x + (size_t)wid * 128 + lane * 2);
    float2 ov = *(const float2*)(o + (size_t)wid * 128 + lane * 2);
    float v0 = xv.x + ov.x, v1 = xv.y + ov.y;
    float s = v0 + v1, ss = v0 * v0 + v1 * v1;
#pragma unroll
    for (int off = 1; off < 64; off <<= 1) {
        s  += __shfl_xor(s,  off, 64);
        ss += __shfl_xor(ss, off, 64);
    }
    float mean = s * (1.f / 128.f);
    float var  = ss * (1.f / 128.f) - mean * mean;
    float rstd = rsqrtf(var + 1e-5f);
    float2 gv = *(const float2*)(g + lane * 2);
    float2 bv = *(const float2*)(b + lane * 2);
    float o0 = (v0 - mean) * rstd * gv.x + bv.x;
    float o1 = (v1 - mean) * rstd * gv.y + bv.y;
    unsigned int w = (unsigned int)f2b(o0) | ((unsigned int)f2b(o1) << 16);
    *(unsigned int*)(h + (size_t)wid * 128 + lane * 2) = w;
}

__global__ __launch_bounds__(256)
void ln2_kernel(const unsigned short* __restrict__ h, const float* __restrict__ ff,
                const float* __restrict__ g, const float* __restrict__ b,
                float* __restrict__ out, int n)
{
    int wid  = (blockIdx.x * blockDim.x + threadIdx.x) >> 6;
    int lane = threadIdx.x & 63;
    if (wid >= n) return;
    unsigned int hw = *(const unsigned int*)(h + (size_t)wid * 128 + lane * 2);
    float2 fv = *(const float2*)(ff + (size_t)wid * 128 + lane * 2);
    float v0 = blo(hw) + fv.x, v1 = bhi(hw) + fv.y;
    float s = v0 + v1, ss = v0 * v0 + v1 * v1;
#pragma unroll
    for (int off = 1; off < 64; off <<= 1) {
        s  += __shfl_xor(s,  off, 64);
        ss += __shfl_xor(ss, off, 64);
    }
    float mean = s * (1.f / 128.f);
    float var  = ss * (1.f / 128.f) - mean * mean;
    float rstd = rsqrtf(var + 1e-5f);
    float2 gv = *(const float2*)(g + lane * 2);
    float2 bv = *(const float2*)(b + lane * 2);
    float2 o;
    o.x = (v0 - mean) * rstd * gv.x + bv.x;
    o.y = (v1 - mean) * rstd * gv.y + bv.y;
    *(float2*)(out + (size_t)wid * 128 + lane * 2) = o;
}

// ---------------------------------------------------------------------------
extern "C" void kernel_launch(void* const* d_in, const int* in_sizes, int n_in,
                              void* d_out, int out_size, void* d_ws, size_t ws_size,
                              hipStream_t stream)
{
    const float* x    = (const float*)d_in[0];
    const float* Wq   = (const float*)d_in[1];
    const float* bq   = (const float*)d_in[2];
    const float* Wk   = (const float*)d_in[3];
    const float* bk   = (const float*)d_in[4];
    const float* Wv   = (const float*)d_in[5];
    const float* bv   = (const float*)d_in[6];
    const float* Wo   = (const float*)d_in[7];
    const float* bo   = (const float*)d_in[8];
    const float* ln1g = (const float*)d_in[9];
    const float* ln1b = (const float*)d_in[10];
    const float* W1   = (const float*)d_in[11];
    const float* b1   = (const float*)d_in[12];
    const float* W2   = (const float*)d_in[13];
    const float* b2   = (const float*)d_in[14];
    const float* ln2g = (const float*)d_in[15];
    const float* ln2b = (const float*)d_in[16];
    const int*   eidx = (const int*)d_in[17];

    const int N_ = in_sizes[0] / 128;
    const int E_ = in_sizes[17] / 2;
    const int Mpad = ((N_ + 127) / 128) * 128;
    const int* srcE = eidx;
    const int* tgtE = eidx + E_;
    float* out = (float*)d_out;

    // workspace layout (bf16 buffers as unsigned short)
    unsigned short* xb   = (unsigned short*)d_ws;                 // [Mpad][128]
    unsigned short* qkvb = xb + (size_t)Mpad * 128;               // [Mpad][384]
    unsigned short* tb   = xb;                                    // alias [Mpad][512] (xb+qkvb dead)
    unsigned short* aggb = qkvb + (size_t)Mpad * 384;             // [Mpad][128]
    unsigned short* hb   = aggb + (size_t)Mpad * 128;             // [Mpad][128]
    float* rawb          = (float*)(hb + (size_t)Mpad * 128);     // [Mpad][128] f32 (o_raw/ff_raw)
    unsigned short* WcatT = (unsigned short*)(rawb + (size_t)Mpad * 128);
    unsigned short* WoT  = WcatT + 384 * 128;
    unsigned short* W1T  = WoT + 128 * 128;
    unsigned short* W2T  = W1T + 512 * 128;
    float* bqkv          = (float*)(W2T + 128 * 512);
    int* deg  = (int*)(bqkv + 384);
    int* scn  = deg + N_;
    int* bsum = scn + N_;
    int* rowp = bsum + 64;
    int* cur  = rowp + N_ + 1;
    int* ssrc = cur + N_;

    hipMemsetAsync(deg, 0, sizeof(int) * N_, stream);
    hipMemsetAsync(cur, 0, sizeof(int) * N_, stream);

    const int nb1024 = (N_ + 1023) / 1024;

    cast_x<<<((size_t)Mpad * 128 / 4 + 255) / 256, 256, 0, stream>>>(x, xb, N_, Mpad);
    cast_w<<<768, 256, 0, stream>>>(Wq, Wk, Wv, Wo, W1, W2, bq, bk, bv,
                                    WcatT, WoT, W1T, W2T, bqkv);

    // QKV fused GEMM: [Mpad x 128] @ [128 x 384]
    mfma_gemm<128, 0, 1><<<dim3(Mpad / 128, 3), 256, 0, stream>>>(xb, WcatT, bqkv, qkvb, N_, 384);

    deg_kernel<<<(E_ + 255) / 256, 256, 0, stream>>>(tgtE, deg, E_);
    scan1<<<nb1024, 1024, 0, stream>>>(deg, scn, bsum, N_);
    scan2<<<1, 64, 0, stream>>>(bsum, nb1024);
    scan3<<<(N_ + 256) / 256, 256, 0, stream>>>(scn, deg, bsum, rowp, N_, E_);
    scatter_kernel<<<(E_ + 255) / 256, 256, 0, stream>>>(srcE, tgtE, rowp, cur, ssrc, E_);

    attn_kernel<<<(Mpad + 3) / 4, 256, 0, stream>>>(qkvb, rowp, ssrc, aggb, N_, Mpad);

    // out_attn @ Wo -> raw (fp32)
    mfma_gemm<128, 0, 0><<<dim3(Mpad / 128, 1), 256, 0, stream>>>(aggb, WoT, bo, rawb, N_, 128);
    ln1_kernel<<<(Mpad + 3) / 4, 256, 0, stream>>>(x, rawb, ln1g, ln1b, hb, N_, Mpad);

    // FF1: relu(h @ W1 + b1) -> t (bf16), FF2: t @ W2 + b2 -> raw (fp32)
    mfma_gemm<128, 1, 1><<<dim3(Mpad / 128, 4), 256, 0, stream>>>(hb, W1T, b1, tb, N_, 512);
    mfma_gemm<512, 0, 0><<<dim3(Mpad / 128, 1), 256, 0, stream>>>(tb, W2T, b2, rawb, N_, 128);

    ln2_kernel<<<((size_t)N_ + 3) / 4, 256, 0, stream>>>(hb, rawb, ln2g, ln2b, out, N_);
}

// Round 3
// 326.311 us; speedup vs baseline: 2.0643x; 1.0499x over previous
//
#include <hip/hip_runtime.h>
#include <math.h>

typedef __attribute__((ext_vector_type(8))) short bf16x8;
typedef __attribute__((ext_vector_type(4))) float f32x4;

__device__ __forceinline__ unsigned short f2b(float f) {
    unsigned int u = __float_as_uint(f);
    unsigned int r = (u + 0x7fffu + ((u >> 16) & 1u)) >> 16;   // RTNE
    return (unsigned short)r;
}
__device__ __forceinline__ float blo(unsigned int w) { return __uint_as_float(w << 16); }
__device__ __forceinline__ float bhi(unsigned int w) { return __uint_as_float(w & 0xffff0000u); }

__device__ __forceinline__ void gload_lds16(const void* g, void* lds) {
    __builtin_amdgcn_global_load_lds(
        (const __attribute__((address_space(1))) unsigned int*)g,
        (__attribute__((address_space(3))) unsigned int*)lds, 16, 0, 0);
}

// ---------------------------------------------------------------------------
// bf16 MFMA GEMM: out[M x NC] = act(A[Mpad x K] @ W[K x NC] + bias)
// BT = W^T row-major [NC x K] bf16. Tile 128x128, BK=64, 4 waves.
// LDS XOR-swizzle (T2): ds_read_b128 row stride is 128 B -> 16-way conflict
// unswizzled; chunk ^= (row&7) makes it 2-way (free). global_load_lds writes
// linearly, so the *global source* chunk is pre-swizzled (rule #21).
// ---------------------------------------------------------------------------
template<int K, int RELU, int OUT_BF16>
__global__ __launch_bounds__(256)
void mfma_gemm(const unsigned short* __restrict__ A,
               const unsigned short* __restrict__ BT,
               const float* __restrict__ bias,
               void* __restrict__ outv, int M, int NC)
{
    __shared__ unsigned short As[128 * 64];
    __shared__ unsigned short Bs[128 * 64];
    const int tid  = threadIdx.x;
    const int lane = tid & 63;
    const int wid  = tid >> 6;
    const int wr = wid >> 1, wc = wid & 1;
    const int rowBase = blockIdx.x * 128;
    const int colBase = blockIdx.y * 128;

    f32x4 acc[4][4];
#pragma unroll
    for (int i = 0; i < 4; ++i)
#pragma unroll
        for (int j = 0; j < 4; ++j) acc[i][j] = (f32x4)0.f;

    // staging geometry: 1024 chunks (16B each) per matrix, 4 per thread.
    // chunk c: row r=c>>3, col-chunk cc=c&7; source k pre-swizzled by r&7.
    int srow[4], skoff[4];
#pragma unroll
    for (int t = 0; t < 4; ++t) {
        int c = tid + t * 256;
        int r = c >> 3, cc = c & 7;
        srow[t]  = r;
        skoff[t] = ((cc ^ (r & 7)) << 3);
    }

    const int rl = lane & 15;
    const int kh = lane >> 4;

    for (int k0 = 0; k0 < K; k0 += 64) {
#pragma unroll
        for (int t = 0; t < 4; ++t) {
            int c = tid + t * 256;
            gload_lds16(A + (size_t)(rowBase + srow[t]) * K + k0 + skoff[t], &As[c * 8]);
            gload_lds16(BT + (size_t)(colBase + srow[t]) * K + k0 + skoff[t], &Bs[c * 8]);
        }
        __syncthreads();

        bf16x8 a[4][2], b[4][2];
#pragma unroll
        for (int mi = 0; mi < 4; ++mi)
#pragma unroll
            for (int kt = 0; kt < 2; ++kt) {
                a[mi][kt] = *(const bf16x8*)&As[(((wr * 64 + mi * 16 + rl) * 64) + kt * 32 + kh * 8) ^ ((rl & 7) << 3)];
                b[mi][kt] = *(const bf16x8*)&Bs[(((wc * 64 + mi * 16 + rl) * 64) + kt * 32 + kh * 8) ^ ((rl & 7) << 3)];
            }
#pragma unroll
        for (int kt = 0; kt < 2; ++kt)
#pragma unroll
            for (int mi = 0; mi < 4; ++mi)
#pragma unroll
                for (int ni = 0; ni < 4; ++ni)
                    acc[mi][ni] = __builtin_amdgcn_mfma_f32_16x16x32_bf16(a[mi][kt], b[ni][kt], acc[mi][ni], 0, 0, 0);
        __syncthreads();
    }

#pragma unroll
    for (int ni = 0; ni < 4; ++ni) {
        const int col = colBase + wc * 64 + ni * 16 + (lane & 15);
        const float bv = bias[col];
#pragma unroll
        for (int mi = 0; mi < 4; ++mi) {
            const int rowb = rowBase + wr * 64 + mi * 16 + (lane >> 4) * 4;
#pragma unroll
            for (int r = 0; r < 4; ++r) {
                const int row = rowb + r;
                if (row >= M) continue;
                float v = acc[mi][ni][r] + bv;
                if (RELU) v = fmaxf(v, 0.f);
                if (OUT_BF16)
                    ((unsigned short*)outv)[(size_t)row * NC + col] = f2b(v);
                else
                    ((float*)outv)[(size_t)row * NC + col] = v;
            }
        }
    }
}

// ---------------------------------------------------------------------------
// casts
// ---------------------------------------------------------------------------
__global__ void cast_x(const float* __restrict__ x, unsigned short* __restrict__ xb,
                       int n, int npad)
{
    size_t i = ((size_t)blockIdx.x * blockDim.x + threadIdx.x) * 4;
    if (i >= (size_t)npad * 128) return;
    float4 v = make_float4(0.f, 0.f, 0.f, 0.f);
    if (i < (size_t)n * 128) v = *(const float4*)(x + i);
    ushort4 o;
    o.x = f2b(v.x); o.y = f2b(v.y); o.z = f2b(v.z); o.w = f2b(v.w);
    *(ushort4*)(xb + i) = o;
}

__global__ void cast_w(const float* __restrict__ Wq, const float* __restrict__ Wk,
                       const float* __restrict__ Wv, const float* __restrict__ Wo,
                       const float* __restrict__ W1, const float* __restrict__ W2,
                       const float* __restrict__ bq, const float* __restrict__ bk,
                       const float* __restrict__ bv,
                       unsigned short* __restrict__ WcatT, unsigned short* __restrict__ WoT,
                       unsigned short* __restrict__ W1T, unsigned short* __restrict__ W2T,
                       float* __restrict__ bqkv)
{
    int i = blockIdx.x * 256 + threadIdx.x;
    if (i < 49152) {                      // WcatT[384][128] = [Wq|Wk|Wv]^T
        int j = i >> 7, k = i & 127;
        const float* W = (j < 128) ? Wq : ((j < 256) ? Wk : Wv);
        WcatT[i] = f2b(W[k * 128 + (j & 127)]);
    } else if (i < 65536) {               // WoT[128][128]
        int t = i - 49152; int j = t >> 7, k = t & 127;
        WoT[t] = f2b(Wo[k * 128 + j]);
    } else if (i < 131072) {              // W1T[512][128], W1 is [128][512]
        int t = i - 65536; int j = t >> 7, k = t & 127;
        W1T[t] = f2b(W1[k * 512 + j]);
    } else if (i < 196608) {              // W2T[128][512], W2 is [512][128]
        int t = i - 131072; int j = t >> 9, k = t & 511;
        W2T[t] = f2b(W2[k * 128 + j]);
    }
    if (i < 384) bqkv[i] = (i < 128) ? bq[i] : ((i < 256) ? bk[i - 128] : bv[i - 256]);
}

// ---------------------------------------------------------------------------
// CSR build: histogram, 3-phase scan, scatter (also emits sorted tgt)
// ---------------------------------------------------------------------------
__global__ void deg_kernel(const int* __restrict__ tgt, int* __restrict__ deg, int E)
{
    int i = blockIdx.x * blockDim.x + threadIdx.x;
    if (i < E) atomicAdd(&deg[tgt[i]], 1);
}

__global__ __launch_bounds__(1024)
void scan1(const int* __restrict__ deg, int* __restrict__ scn, int* __restrict__ bsum, int n)
{
    __shared__ int sh[1024];
    int gid = blockIdx.x * 1024 + threadIdx.x;
    int v = (gid < n) ? deg[gid] : 0;
    sh[threadIdx.x] = v;
    __syncthreads();
    for (int off = 1; off < 1024; off <<= 1) {
        int y = (threadIdx.x >= off) ? sh[threadIdx.x - off] : 0;
        __syncthreads();
        sh[threadIdx.x] += y;
        __syncthreads();
    }
    if (gid < n) scn[gid] = sh[threadIdx.x];
    if (threadIdx.x == 1023) bsum[blockIdx.x] = sh[1023];
}

__global__ void scan2(int* __restrict__ bsum, int nb)
{
    if (threadIdx.x == 0) {
        int acc = 0;
        for (int i = 0; i < nb; ++i) { int t = bsum[i]; bsum[i] = acc; acc += t; }
    }
}

__global__ void scan3(const int* __restrict__ scn, const int* __restrict__ deg,
                      const int* __restrict__ bsum, int* __restrict__ rowp, int n, int E)
{
    int gid = blockIdx.x * blockDim.x + threadIdx.x;
    if (gid < n) rowp[gid] = bsum[gid >> 10] + scn[gid] - deg[gid];
    if (gid == n) rowp[n] = E;
}

__global__ void scatter_kernel(const int* __restrict__ src, const int* __restrict__ tgt,
                               const int* __restrict__ rowp, int* __restrict__ cursor,
                               int* __restrict__ ssrc, int* __restrict__ stgt, int E)
{
    int i = blockIdx.x * blockDim.x + threadIdx.x;
    if (i < E) {
        int t = tgt[i];
        int pos = rowp[t] + atomicAdd(&cursor[t], 1);
        ssrc[pos] = src[i];
        stgt[pos] = t;
    }
}

// ---------------------------------------------------------------------------
// Edge-parallel score kernel: 16 lanes per sorted edge, lane el holds dims
// el*8..el*8+7. head = el>>1. Pre-scales by 1/sqrt(DK) * log2(e) for exp2.
// ---------------------------------------------------------------------------
#define SCORE_SCALE 0.360673760222241f   // 0.25 * log2(e)

__global__ __launch_bounds__(256)
void score_kernel(const unsigned short* __restrict__ qkv, const int* __restrict__ ssrc,
                  const int* __restrict__ stgt, float* __restrict__ scores, int E)
{
    int gw = (blockIdx.x * 256 + threadIdx.x) >> 4;   // edge position
    int el = threadIdx.x & 15;
    if (gw >= E) return;
    int s = ssrc[gw], t = stgt[gw];
    uint4 qv = *(const uint4*)(qkv + (size_t)t * 384 + el * 8);
    uint4 kv = *(const uint4*)(qkv + (size_t)s * 384 + 128 + el * 8);
    float d;
    d  = blo(qv.x) * blo(kv.x) + bhi(qv.x) * bhi(kv.x);
    d += blo(qv.y) * blo(kv.y) + bhi(qv.y) * bhi(kv.y);
    d += blo(qv.z) * blo(kv.z) + bhi(qv.z) * bhi(kv.z);
    d += blo(qv.w) * blo(kv.w) + bhi(qv.w) * bhi(kv.w);
    d += __shfl_xor(d, 1, 64);
    if ((el & 1) == 0)
        scores[(size_t)gw * 8 + (el >> 1)] = d * SCORE_SCALE;
}

// ---------------------------------------------------------------------------
// Aggregation: wave per target node, online softmax (base 2), 4-edge unroll.
// Lane holds dims 2l,2l+1; head = lane>>3.
// ---------------------------------------------------------------------------
__global__ __launch_bounds__(256)
void attn_agg(const unsigned short* __restrict__ qkv, const int* __restrict__ rowp,
              const int* __restrict__ ssrc, const float* __restrict__ scores,
              unsigned short* __restrict__ agg, int n, int npad)
{
    int wid  = (blockIdx.x * blockDim.x + threadIdx.x) >> 6;
    int lane = threadIdx.x & 63;
    if (wid >= npad) return;
    if (wid >= n) { *(unsigned int*)(agg + (size_t)wid * 128 + lane * 2) = 0u; return; }

    const int head = lane >> 3;
    int e = rowp[wid];
    const int e1 = rowp[wid + 1];

    float m = -INFINITY, l = 0.f, a0 = 0.f, a1 = 0.f;

    for (; e + 4 <= e1; e += 4) {
        int s0 = ssrc[e], s1 = ssrc[e + 1], s2 = ssrc[e + 2], s3 = ssrc[e + 3];
        float sc0 = scores[(size_t)e * 8 + head];
        float sc1 = scores[(size_t)(e + 1) * 8 + head];
        float sc2 = scores[(size_t)(e + 2) * 8 + head];
        float sc3 = scores[(size_t)(e + 3) * 8 + head];
        unsigned int v0 = *(const unsigned int*)(qkv + (size_t)s0 * 384 + 256 + lane * 2);
        unsigned int v1 = *(const unsigned int*)(qkv + (size_t)s1 * 384 + 256 + lane * 2);
        unsigned int v2 = *(const unsigned int*)(qkv + (size_t)s2 * 384 + 256 + lane * 2);
        unsigned int v3 = *(const unsigned int*)(qkv + (size_t)s3 * 384 + 256 + lane * 2);
        float mn = fmaxf(fmaxf(fmaxf(sc0, sc1), fmaxf(sc2, sc3)), m);
        float scale = exp2f(m - mn);
        float w0 = exp2f(sc0 - mn), w1 = exp2f(sc1 - mn);
        float w2 = exp2f(sc2 - mn), w3 = exp2f(sc3 - mn);
        l  = l * scale + ((w0 + w1) + (w2 + w3));
        a0 = a0 * scale + (w0 * blo(v0) + w1 * blo(v1)) + (w2 * blo(v2) + w3 * blo(v3));
        a1 = a1 * scale + (w0 * bhi(v0) + w1 * bhi(v1)) + (w2 * bhi(v2) + w3 * bhi(v3));
        m = mn;
    }
    for (; e < e1; ++e) {
        int s = ssrc[e];
        float sc = scores[(size_t)e * 8 + head];
        unsigned int vw = *(const unsigned int*)(qkv + (size_t)s * 384 + 256 + lane * 2);
        float mn = fmaxf(m, sc);
        float scale = exp2f(m - mn);
        float w = exp2f(sc - mn);
        l  = l * scale + w;
        a0 = a0 * scale + w * blo(vw);
        a1 = a1 * scale + w * bhi(vw);
        m = mn;
    }
    float inv = 1.f / (l + 1e-16f);
    unsigned int o = (unsigned int)f2b(a0 * inv) | ((unsigned int)f2b(a1 * inv) << 16);
    *(unsigned int*)(agg + (size_t)wid * 128 + lane * 2) = o;
}

// ---------------------------------------------------------------------------
// LayerNorm kernels, wave per row (64 lanes x 2 dims)
// ---------------------------------------------------------------------------
__global__ __launch_bounds__(256)
void ln1_kernel(const float* __restrict__ x, const float* __restrict__ o,
                const float* __restrict__ g, const float* __restrict__ b,
                unsigned short* __restrict__ h, int n, int npad)
{
    int wid  = (blockIdx.x * blockDim.x + threadIdx.x) >> 6;
    int lane = threadIdx.x & 63;
    if (wid >= npad) return;
    if (wid >= n) { *(unsigned int*)(h + (size_t)wid * 128 + lane * 2) = 0u; return; }
    float2 xv = *(const float2*)(x + (size_t)wid * 128 + lane * 2);
    float2 ov = *(const float2*)(o + (size_t)wid * 128 + lane * 2);
    float v0 = xv.x + ov.x, v1 = xv.y + ov.y;
    float s = v0 + v1, ss = v0 * v0 + v1 * v1;
#pragma unroll
    for (int off = 1; off < 64; off <<= 1) {
        s  += __shfl_xor(s,  off, 64);
        ss += __shfl_xor(ss, off, 64);
    }
    float mean = s * (1.f / 128.f);
    float var  = ss * (1.f / 128.f) - mean * mean;
    float rstd = rsqrtf(var + 1e-5f);
    float2 gv = *(const float2*)(g + lane * 2);
    float2 bv = *(const float2*)(b + lane * 2);
    float o0 = (v0 - mean) * rstd * gv.x + bv.x;
    float o1 = (v1 - mean) * rstd * gv.y + bv.y;
    unsigned int w = (unsigned int)f2b(o0) | ((unsigned int)f2b(o1) << 16);
    *(unsigned int*)(h + (size_t)wid * 128 + lane * 2) = w;
}

__global__ __launch_bounds__(256)
void ln2_kernel(const unsigned short* __restrict__ h, const float* __restrict__ ff,
                const float* __restrict__ g, const float* __restrict__ b,
                float* __restrict__ out, int n)
{
    int wid  = (blockIdx.x * blockDim.x + threadIdx.x) >> 6;
    int lane = threadIdx.x & 63;
    if (wid >= n) return;
    unsigned int hw = *(const unsigned int*)(h + (size_t)wid * 128 + lane * 2);
    float2 fv = *(const float2*)(ff + (size_t)wid * 128 + lane * 2);
    float v0 = blo(hw) + fv.x, v1 = bhi(hw) + fv.y;
    float s = v0 + v1, ss = v0 * v0 + v1 * v1;
#pragma unroll
    for (int off = 1; off < 64; off <<= 1) {
        s  += __shfl_xor(s,  off, 64);
        ss += __shfl_xor(ss, off, 64);
    }
    float mean = s * (1.f / 128.f);
    float var  = ss * (1.f / 128.f) - mean * mean;
    float rstd = rsqrtf(var + 1e-5f);
    float2 gv = *(const float2*)(g + lane * 2);
    float2 bv = *(const float2*)(b + lane * 2);
    float2 o;
    o.x = (v0 - mean) * rstd * gv.x + bv.x;
    o.y = (v1 - mean) * rstd * gv.y + bv.y;
    *(float2*)(out + (size_t)wid * 128 + lane * 2) = o;
}

// ---------------------------------------------------------------------------
extern "C" void kernel_launch(void* const* d_in, const int* in_sizes, int n_in,
                              void* d_out, int out_size, void* d_ws, size_t ws_size,
                              hipStream_t stream)
{
    const float* x    = (const float*)d_in[0];
    const float* Wq   = (const float*)d_in[1];
    const float* bq   = (const float*)d_in[2];
    const float* Wk   = (const float*)d_in[3];
    const float* bk   = (const float*)d_in[4];
    const float* Wv   = (const float*)d_in[5];
    const float* bv   = (const float*)d_in[6];
    const float* Wo   = (const float*)d_in[7];
    const float* bo   = (const float*)d_in[8];
    const float* ln1g = (const float*)d_in[9];
    const float* ln1b = (const float*)d_in[10];
    const float* W1   = (const float*)d_in[11];
    const float* b1   = (const float*)d_in[12];
    const float* W2   = (const float*)d_in[13];
    const float* b2   = (const float*)d_in[14];
    const float* ln2g = (const float*)d_in[15];
    const float* ln2b = (const float*)d_in[16];
    const int*   eidx = (const int*)d_in[17];

    const int N_ = in_sizes[0] / 128;
    const int E_ = in_sizes[17] / 2;
    const int Mpad = ((N_ + 127) / 128) * 128;
    const int* srcE = eidx;
    const int* tgtE = eidx + E_;
    float* out = (float*)d_out;

    // workspace layout (bf16 buffers as unsigned short)
    unsigned short* xb   = (unsigned short*)d_ws;                 // [Mpad][128]
    unsigned short* qkvb = xb + (size_t)Mpad * 128;               // [Mpad][384]
    unsigned short* tb   = xb;                                    // alias [Mpad][512] (xb+qkvb dead)
    unsigned short* aggb = qkvb + (size_t)Mpad * 384;             // [Mpad][128]
    unsigned short* hb   = aggb + (size_t)Mpad * 128;             // [Mpad][128]
    float* rawb          = (float*)(hb + (size_t)Mpad * 128);     // [Mpad][128] f32
    float* scores        = rawb;                                  // alias [E][8] f32 (dead before rawb written)
    unsigned short* WcatT = (unsigned short*)(rawb + (size_t)Mpad * 128);
    unsigned short* WoT  = WcatT + 384 * 128;
    unsigned short* W1T  = WoT + 128 * 128;
    unsigned short* W2T  = W1T + 512 * 128;
    float* bqkv          = (float*)(W2T + 128 * 512);
    int* deg  = (int*)(bqkv + 384);
    int* scn  = deg + N_;
    int* bsum = scn + N_;
    int* rowp = bsum + 64;
    int* cur  = rowp + N_ + 1;
    int* ssrc = cur + N_;
    int* stgt = ssrc + E_;

    hipMemsetAsync(deg, 0, sizeof(int) * N_, stream);
    hipMemsetAsync(cur, 0, sizeof(int) * N_, stream);

    const int nb1024 = (N_ + 1023) / 1024;

    cast_x<<<((size_t)Mpad * 128 / 4 + 255) / 256, 256, 0, stream>>>(x, xb, N_, Mpad);
    cast_w<<<768, 256, 0, stream>>>(Wq, Wk, Wv, Wo, W1, W2, bq, bk, bv,
                                    WcatT, WoT, W1T, W2T, bqkv);

    // QKV fused GEMM: [Mpad x 128] @ [128 x 384]
    mfma_gemm<128, 0, 1><<<dim3(Mpad / 128, 3), 256, 0, stream>>>(xb, WcatT, bqkv, qkvb, N_, 384);

    deg_kernel<<<(E_ + 255) / 256, 256, 0, stream>>>(tgtE, deg, E_);
    scan1<<<nb1024, 1024, 0, stream>>>(deg, scn, bsum, N_);
    scan2<<<1, 64, 0, stream>>>(bsum, nb1024);
    scan3<<<(N_ + 256) / 256, 256, 0, stream>>>(scn, deg, bsum, rowp, N_, E_);
    scatter_kernel<<<(E_ + 255) / 256, 256, 0, stream>>>(srcE, tgtE, rowp, cur, ssrc, stgt, E_);

    score_kernel<<<((size_t)E_ * 16 + 255) / 256, 256, 0, stream>>>(qkvb, ssrc, stgt, scores, E_);
    attn_agg<<<(Mpad + 3) / 4, 256, 0, stream>>>(qkvb, rowp, ssrc, scores, aggb, N_, Mpad);

    // out_attn @ Wo -> raw (fp32)   [overwrites the scores alias]
    mfma_gemm<128, 0, 0><<<dim3(Mpad / 128, 1), 256, 0, stream>>>(aggb, WoT, bo, rawb, N_, 128);
    ln1_kernel<<<(Mpad + 3) / 4, 256, 0, stream>>>(x, rawb, ln1g, ln1b, hb, N_, Mpad);

    // FF1: relu(h @ W1 + b1) -> t (bf16), FF2: t @ W2 + b2 -> raw (fp32)
    mfma_gemm<128, 1, 1><<<dim3(Mpad / 128, 4), 256, 0, stream>>>(hb, W1T, b1, tb, N_, 512);
    mfma_gemm<512, 0, 0><<<dim3(Mpad / 128, 1), 256, 0, stream>>>(tb, W2T, b2, rawb, N_, 128);

    ln2_kernel<<<((size_t)N_ + 3) / 4, 256, 0, stream>>>(hb, rawb, ln2g, ln2b, out, N_);
}

// Round 4
// 281.220 us; speedup vs baseline: 2.3953x; 1.1603x over previous
//
#include <hip/hip_runtime.h>
#include <math.h>

typedef __attribute__((ext_vector_type(8))) short bf16x8;
typedef __attribute__((ext_vector_type(4))) float f32x4;

__device__ __forceinline__ unsigned short f2b(float f) {
    unsigned int u = __float_as_uint(f);
    unsigned int r = (u + 0x7fffu + ((u >> 16) & 1u)) >> 16;   // RTNE
    return (unsigned short)r;
}
__device__ __forceinline__ float blo(unsigned int w) { return __uint_as_float(w << 16); }
__device__ __forceinline__ float bhi(unsigned int w) { return __uint_as_float(w & 0xffff0000u); }
__device__ __forceinline__ float b2f(unsigned short u) { return __uint_as_float((unsigned int)u << 16); }

__device__ __forceinline__ void gload_lds16(const void* g, void* lds) {
    __builtin_amdgcn_global_load_lds(
        (const __attribute__((address_space(1))) unsigned int*)g,
        (__attribute__((address_space(3))) unsigned int*)lds, 16, 0, 0);
}

// ---------------------------------------------------------------------------
// bf16 MFMA GEMM: out[M x NC] = epi(A[Mpad x K] @ W[K x NC] + bias)
// BT = W^T row-major [NC x K] bf16. Tile 128x128, BK=64, 4 waves, T2 swizzle.
// EPI: 1 = relu -> bf16 ws (unguarded, Mpad rows)
//      2 = bias -> bf16 ws (unguarded, Mpad rows)
//      3 = +res(f32) + LayerNorm -> bf16 ws (pad rows zeroed)   [NC==128]
//      4 = +res(bf16) + LayerNorm -> f32 out (guard row<M)      [NC==128]
// ---------------------------------------------------------------------------
template<int K, int EPI>
__global__ __launch_bounds__(256)
void mfma_gemm(const unsigned short* __restrict__ A,
               const unsigned short* __restrict__ BT,
               const float* __restrict__ bias,
               const void* __restrict__ res,
               const float* __restrict__ lng,
               const float* __restrict__ lnb,
               void* __restrict__ outv, int M, int NC)
{
    __shared__ unsigned short As[128 * 64];
    __shared__ unsigned short Bs[128 * 64];
    const int tid  = threadIdx.x;
    const int lane = tid & 63;
    const int wid  = tid >> 6;
    const int wr = wid >> 1, wc = wid & 1;
    const int rowBase = blockIdx.x * 128;
    const int colBase = blockIdx.y * 128;

    f32x4 acc[4][4];
#pragma unroll
    for (int i = 0; i < 4; ++i)
#pragma unroll
        for (int j = 0; j < 4; ++j) acc[i][j] = (f32x4)0.f;

    // staging geometry: 1024 chunks (16B each) per matrix, 4 per thread.
    int srow[4], skoff[4];
#pragma unroll
    for (int t = 0; t < 4; ++t) {
        int c = tid + t * 256;
        int r = c >> 3, cc = c & 7;
        srow[t]  = r;
        skoff[t] = ((cc ^ (r & 7)) << 3);
    }

    const int rl = lane & 15;
    const int kh = lane >> 4;

    for (int k0 = 0; k0 < K; k0 += 64) {
#pragma unroll
        for (int t = 0; t < 4; ++t) {
            int c = tid + t * 256;
            gload_lds16(A + (size_t)(rowBase + srow[t]) * K + k0 + skoff[t], &As[c * 8]);
            gload_lds16(BT + (size_t)(colBase + srow[t]) * K + k0 + skoff[t], &Bs[c * 8]);
        }
        __syncthreads();

        bf16x8 a[4][2], b[4][2];
#pragma unroll
        for (int mi = 0; mi < 4; ++mi)
#pragma unroll
            for (int kt = 0; kt < 2; ++kt) {
                a[mi][kt] = *(const bf16x8*)&As[(((wr * 64 + mi * 16 + rl) * 64) + kt * 32 + kh * 8) ^ ((rl & 7) << 3)];
                b[mi][kt] = *(const bf16x8*)&Bs[(((wc * 64 + mi * 16 + rl) * 64) + kt * 32 + kh * 8) ^ ((rl & 7) << 3)];
            }
#pragma unroll
        for (int kt = 0; kt < 2; ++kt)
#pragma unroll
            for (int mi = 0; mi < 4; ++mi)
#pragma unroll
                for (int ni = 0; ni < 4; ++ni)
                    acc[mi][ni] = __builtin_amdgcn_mfma_f32_16x16x32_bf16(a[mi][kt], b[ni][kt], acc[mi][ni], 0, 0, 0);
        __syncthreads();
    }

    if (EPI == 3 || EPI == 4) {
        // fused residual + LayerNorm epilogue (NC==128, colBase==0).
        float* ls = (float*)As;            // [128][2] row-sum halves, then [128][2] sumsq
        float bb[4], gg[4], be[4];
#pragma unroll
        for (int ni = 0; ni < 4; ++ni) {
            int col = wc * 64 + ni * 16 + rl;
            bb[ni] = bias[col];
            gg[ni] = lng[col];
            be[ni] = lnb[col];
        }
#pragma unroll
        for (int mi = 0; mi < 4; ++mi) {
#pragma unroll
            for (int r = 0; r < 4; ++r) {
                int lrow = wr * 64 + mi * 16 + kh * 4 + r;
                int row  = rowBase + lrow;
                float s = 0.f, ss = 0.f;
#pragma unroll
                for (int ni = 0; ni < 4; ++ni) {
                    int col = wc * 64 + ni * 16 + rl;
                    float rr = 0.f;
                    if (row < M) {
                        if (EPI == 3) rr = ((const float*)res)[(size_t)row * 128 + col];
                        else          rr = b2f(((const unsigned short*)res)[(size_t)row * 128 + col]);
                    }
                    float v = acc[mi][ni][r] + bb[ni] + rr;
                    acc[mi][ni][r] = v;
                    s += v; ss += v * v;
                }
#pragma unroll
                for (int off = 1; off < 16; off <<= 1) {
                    s  += __shfl_xor(s,  off, 64);
                    ss += __shfl_xor(ss, off, 64);
                }
                if (rl == 0) {
                    ls[lrow * 2 + wc]       = s;
                    ls[256 + lrow * 2 + wc] = ss;
                }
            }
        }
        __syncthreads();
#pragma unroll
        for (int mi = 0; mi < 4; ++mi) {
#pragma unroll
            for (int r = 0; r < 4; ++r) {
                int lrow = wr * 64 + mi * 16 + kh * 4 + r;
                int row  = rowBase + lrow;
                float s  = ls[lrow * 2] + ls[lrow * 2 + 1];
                float ss = ls[256 + lrow * 2] + ls[256 + lrow * 2 + 1];
                float mean = s * (1.f / 128.f);
                float var  = ss * (1.f / 128.f) - mean * mean;
                float rstd = rsqrtf(var + 1e-5f);
#pragma unroll
                for (int ni = 0; ni < 4; ++ni) {
                    int col = wc * 64 + ni * 16 + rl;
                    float o = (acc[mi][ni][r] - mean) * rstd * gg[ni] + be[ni];
                    if (EPI == 3) {
                        ((unsigned short*)outv)[(size_t)row * 128 + col] = (row < M) ? f2b(o) : (unsigned short)0;
                    } else {
                        if (row < M) ((float*)outv)[(size_t)row * 128 + col] = o;
                    }
                }
            }
        }
    } else {
        // plain epilogue -> bf16 workspace, write all Mpad rows
#pragma unroll
        for (int ni = 0; ni < 4; ++ni) {
            const int col = colBase + wc * 64 + ni * 16 + rl;
            const float bv = bias[col];
#pragma unroll
            for (int mi = 0; mi < 4; ++mi) {
                const int rowb = rowBase + wr * 64 + mi * 16 + kh * 4;
#pragma unroll
                for (int r = 0; r < 4; ++r) {
                    float v = acc[mi][ni][r] + bv;
                    if (EPI == 1) v = fmaxf(v, 0.f);
                    ((unsigned short*)outv)[(size_t)(rowb + r) * NC + col] = f2b(v);
                }
            }
        }
    }
}

// ---------------------------------------------------------------------------
// fused input casts: grid = xblocks (cast x) + 768 (cast/transpose weights)
// ---------------------------------------------------------------------------
__global__ void cast_all(const float* __restrict__ x, unsigned short* __restrict__ xb,
                         int n, int npad, int xblocks,
                         const float* __restrict__ Wq, const float* __restrict__ Wk,
                         const float* __restrict__ Wv, const float* __restrict__ Wo,
                         const float* __restrict__ W1, const float* __restrict__ W2,
                         const float* __restrict__ bq, const float* __restrict__ bk,
                         const float* __restrict__ bv,
                         unsigned short* __restrict__ WcatT, unsigned short* __restrict__ WoT,
                         unsigned short* __restrict__ W1T, unsigned short* __restrict__ W2T,
                         float* __restrict__ bqkv)
{
    if (blockIdx.x < (unsigned)xblocks) {
        size_t i = ((size_t)blockIdx.x * 256 + threadIdx.x) * 4;
        if (i >= (size_t)npad * 128) return;
        float4 v = make_float4(0.f, 0.f, 0.f, 0.f);
        if (i < (size_t)n * 128) v = *(const float4*)(x + i);
        ushort4 o;
        o.x = f2b(v.x); o.y = f2b(v.y); o.z = f2b(v.z); o.w = f2b(v.w);
        *(ushort4*)(xb + i) = o;
        return;
    }
    int i = (blockIdx.x - xblocks) * 256 + threadIdx.x;
    if (i < 49152) {                      // WcatT[384][128] = [Wq|Wk|Wv]^T
        int j = i >> 7, k = i & 127;
        const float* W = (j < 128) ? Wq : ((j < 256) ? Wk : Wv);
        WcatT[i] = f2b(W[k * 128 + (j & 127)]);
    } else if (i < 65536) {               // WoT[128][128]
        int t = i - 49152; int j = t >> 7, k = t & 127;
        WoT[t] = f2b(Wo[k * 128 + j]);
    } else if (i < 131072) {              // W1T[512][128], W1 is [128][512]
        int t = i - 65536; int j = t >> 7, k = t & 127;
        W1T[t] = f2b(W1[k * 512 + j]);
    } else if (i < 196608) {              // W2T[128][512], W2 is [512][128]
        int t = i - 131072; int j = t >> 9, k = t & 511;
        W2T[t] = f2b(W2[k * 128 + j]);
    }
    if (i < 384) bqkv[i] = (i < 128) ? bq[i] : ((i < 256) ? bk[i - 128] : bv[i - 256]);
}

// ---------------------------------------------------------------------------
// CSR build: histogram, 3-phase scan, scatter (packed int2 edge records)
// ---------------------------------------------------------------------------
__global__ void deg_kernel(const int* __restrict__ tgt, int* __restrict__ deg, int E)
{
    int i = blockIdx.x * blockDim.x + threadIdx.x;
    if (i < E) atomicAdd(&deg[tgt[i]], 1);
}

__global__ __launch_bounds__(1024)
void scan1(const int* __restrict__ deg, int* __restrict__ scn, int* __restrict__ bsum, int n)
{
    __shared__ int sh[1024];
    int gid = blockIdx.x * 1024 + threadIdx.x;
    int v = (gid < n) ? deg[gid] : 0;
    sh[threadIdx.x] = v;
    __syncthreads();
    for (int off = 1; off < 1024; off <<= 1) {
        int y = (threadIdx.x >= off) ? sh[threadIdx.x - off] : 0;
        __syncthreads();
        sh[threadIdx.x] += y;
        __syncthreads();
    }
    if (gid < n) scn[gid] = sh[threadIdx.x];
    if (threadIdx.x == 1023) bsum[blockIdx.x] = sh[1023];
}

__global__ void scan2(int* __restrict__ bsum, int nb)
{
    if (threadIdx.x == 0) {
        int acc = 0;
        for (int i = 0; i < nb; ++i) { int t = bsum[i]; bsum[i] = acc; acc += t; }
    }
}

__global__ void scan3(const int* __restrict__ scn, const int* __restrict__ deg,
                      const int* __restrict__ bsum, int* __restrict__ rowp,
                      int* __restrict__ cur, int n, int E)
{
    int gid = blockIdx.x * blockDim.x + threadIdx.x;
    if (gid < n) {
        int v = bsum[gid >> 10] + scn[gid] - deg[gid];
        rowp[gid] = v;
        cur[gid]  = v;
    }
    if (gid == n) rowp[n] = E;
}

__global__ void scatter_kernel(const int* __restrict__ src, const int* __restrict__ tgt,
                               int* __restrict__ cur, int2* __restrict__ epos, int E)
{
    int i = blockIdx.x * blockDim.x + threadIdx.x;
    if (i < E) {
        int t = tgt[i];
        int pos = atomicAdd(&cur[t], 1);
        epos[pos] = make_int2(src[i], t);
    }
}

// ---------------------------------------------------------------------------
// Edge-parallel score kernel: 16 lanes per sorted edge, lane el holds dims
// el*8..el*8+7. head = el>>1. Pre-scales by 1/sqrt(DK) * log2(e) for exp2.
// ---------------------------------------------------------------------------
#define SCORE_SCALE 0.360673760222241f   // 0.25 * log2(e)

__global__ __launch_bounds__(256)
void score_kernel(const unsigned short* __restrict__ qkv, const int2* __restrict__ epos,
                  float* __restrict__ scores, int E)
{
    int gw = (blockIdx.x * 256 + threadIdx.x) >> 4;   // edge position
    int el = threadIdx.x & 15;
    if (gw >= E) return;
    int2 st = epos[gw];
    uint4 qv = *(const uint4*)(qkv + (size_t)st.y * 384 + el * 8);
    uint4 kv = *(const uint4*)(qkv + (size_t)st.x * 384 + 128 + el * 8);
    float d;
    d  = blo(qv.x) * blo(kv.x) + bhi(qv.x) * bhi(kv.x);
    d += blo(qv.y) * blo(kv.y) + bhi(qv.y) * bhi(kv.y);
    d += blo(qv.z) * blo(kv.z) + bhi(qv.z) * bhi(kv.z);
    d += blo(qv.w) * blo(kv.w) + bhi(qv.w) * bhi(kv.w);
    d += __shfl_xor(d, 1, 64);
    if ((el & 1) == 0)
        scores[(size_t)gw * 8 + (el >> 1)] = d * SCORE_SCALE;
}

// ---------------------------------------------------------------------------
// Aggregation: wave per target node, online softmax (base 2), 4-edge unroll.
// Lane holds dims 2l,2l+1; head = lane>>3.
// ---------------------------------------------------------------------------
__global__ __launch_bounds__(256)
void attn_agg(const unsigned short* __restrict__ qkv, const int* __restrict__ rowp,
              const int2* __restrict__ epos, const float* __restrict__ scores,
              unsigned short* __restrict__ agg, int n, int npad)
{
    int wid  = (blockIdx.x * blockDim.x + threadIdx.x) >> 6;
    int lane = threadIdx.x & 63;
    if (wid >= npad) return;
    if (wid >= n) { *(unsigned int*)(agg + (size_t)wid * 128 + lane * 2) = 0u; return; }

    const int head = lane >> 3;
    int e = rowp[wid];
    const int e1 = rowp[wid + 1];

    float m = -INFINITY, l = 0.f, a0 = 0.f, a1 = 0.f;

    for (; e + 4 <= e1; e += 4) {
        int s0 = epos[e].x, s1 = epos[e + 1].x, s2 = epos[e + 2].x, s3 = epos[e + 3].x;
        float sc0 = scores[(size_t)e * 8 + head];
        float sc1 = scores[(size_t)(e + 1) * 8 + head];
        float sc2 = scores[(size_t)(e + 2) * 8 + head];
        float sc3 = scores[(size_t)(e + 3) * 8 + head];
        unsigned int v0 = *(const unsigned int*)(qkv + (size_t)s0 * 384 + 256 + lane * 2);
        unsigned int v1 = *(const unsigned int*)(qkv + (size_t)s1 * 384 + 256 + lane * 2);
        unsigned int v2 = *(const unsigned int*)(qkv + (size_t)s2 * 384 + 256 + lane * 2);
        unsigned int v3 = *(const unsigned int*)(qkv + (size_t)s3 * 384 + 256 + lane * 2);
        float mn = fmaxf(fmaxf(fmaxf(sc0, sc1), fmaxf(sc2, sc3)), m);
        float scale = exp2f(m - mn);
        float w0 = exp2f(sc0 - mn), w1 = exp2f(sc1 - mn);
        float w2 = exp2f(sc2 - mn), w3 = exp2f(sc3 - mn);
        l  = l * scale + ((w0 + w1) + (w2 + w3));
        a0 = a0 * scale + (w0 * blo(v0) + w1 * blo(v1)) + (w2 * blo(v2) + w3 * blo(v3));
        a1 = a1 * scale + (w0 * bhi(v0) + w1 * bhi(v1)) + (w2 * bhi(v2) + w3 * bhi(v3));
        m = mn;
    }
    for (; e < e1; ++e) {
        int s = epos[e].x;
        float sc = scores[(size_t)e * 8 + head];
        unsigned int vw = *(const unsigned int*)(qkv + (size_t)s * 384 + 256 + lane * 2);
        float mn = fmaxf(m, sc);
        float scale = exp2f(m - mn);
        float w = exp2f(sc - mn);
        l  = l * scale + w;
        a0 = a0 * scale + w * blo(vw);
        a1 = a1 * scale + w * bhi(vw);
        m = mn;
    }
    float inv = 1.f / (l + 1e-16f);
    unsigned int o = (unsigned int)f2b(a0 * inv) | ((unsigned int)f2b(a1 * inv) << 16);
    *(unsigned int*)(agg + (size_t)wid * 128 + lane * 2) = o;
}

// ---------------------------------------------------------------------------
extern "C" void kernel_launch(void* const* d_in, const int* in_sizes, int n_in,
                              void* d_out, int out_size, void* d_ws, size_t ws_size,
                              hipStream_t stream)
{
    const float* x    = (const float*)d_in[0];
    const float* Wq   = (const float*)d_in[1];
    const float* bq   = (const float*)d_in[2];
    const float* Wk   = (const float*)d_in[3];
    const float* bk   = (const float*)d_in[4];
    const float* Wv   = (const float*)d_in[5];
    const float* bv   = (const float*)d_in[6];
    const float* Wo   = (const float*)d_in[7];
    const float* bo   = (const float*)d_in[8];
    const float* ln1g = (const float*)d_in[9];
    const float* ln1b = (const float*)d_in[10];
    const float* W1   = (const float*)d_in[11];
    const float* b1   = (const float*)d_in[12];
    const float* W2   = (const float*)d_in[13];
    const float* b2   = (const float*)d_in[14];
    const float* ln2g = (const float*)d_in[15];
    const float* ln2b = (const float*)d_in[16];
    const int*   eidx = (const int*)d_in[17];

    const int N_ = in_sizes[0] / 128;
    const int E_ = in_sizes[17] / 2;
    const int Mpad = ((N_ + 127) / 128) * 128;
    const int* srcE = eidx;
    const int* tgtE = eidx + E_;
    float* out = (float*)d_out;

    // workspace layout
    unsigned short* xb   = (unsigned short*)d_ws;                 // [Mpad][128]
    unsigned short* qkvb = xb + (size_t)Mpad * 128;               // [Mpad][384]
    unsigned short* tb   = xb;                                    // alias [Mpad][512] (xb+qkvb dead)
    unsigned short* aggb = qkvb + (size_t)Mpad * 384;             // [Mpad][128]
    unsigned short* hb   = aggb + (size_t)Mpad * 128;             // [Mpad][128]
    float* scores        = (float*)(hb + (size_t)Mpad * 128);     // [E][8] f32
    unsigned short* WcatT = (unsigned short*)(scores + (size_t)E_ * 8);
    unsigned short* WoT  = WcatT + 384 * 128;
    unsigned short* W1T  = WoT + 128 * 128;
    unsigned short* W2T  = W1T + 512 * 128;
    float* bqkv          = (float*)(W2T + 128 * 512);
    int2* epos           = (int2*)(bqkv + 384);                   // [E] packed (src,tgt)
    int* deg  = (int*)(epos + E_);
    int* scn  = deg + N_;
    int* bsum = scn + N_;
    int* rowp = bsum + 64;
    int* cur  = rowp + N_ + 1;

    hipMemsetAsync(deg, 0, sizeof(int) * N_, stream);

    const int nb1024 = (N_ + 1023) / 1024;
    const int xblocks = (int)(((size_t)Mpad * 128 / 4 + 255) / 256);

    cast_all<<<xblocks + 768, 256, 0, stream>>>(x, xb, N_, Mpad, xblocks,
                                                Wq, Wk, Wv, Wo, W1, W2, bq, bk, bv,
                                                WcatT, WoT, W1T, W2T, bqkv);

    // QKV fused GEMM: [Mpad x 128] @ [128 x 384]
    mfma_gemm<128, 2><<<dim3(Mpad / 128, 3), 256, 0, stream>>>(
        xb, WcatT, bqkv, nullptr, nullptr, nullptr, qkvb, N_, 384);

    deg_kernel<<<(E_ + 255) / 256, 256, 0, stream>>>(tgtE, deg, E_);
    scan1<<<nb1024, 1024, 0, stream>>>(deg, scn, bsum, N_);
    scan2<<<1, 64, 0, stream>>>(bsum, nb1024);
    scan3<<<(N_ + 256) / 256, 256, 0, stream>>>(scn, deg, bsum, rowp, cur, N_, E_);
    scatter_kernel<<<(E_ + 255) / 256, 256, 0, stream>>>(srcE, tgtE, cur, epos, E_);

    score_kernel<<<((size_t)E_ * 16 + 255) / 256, 256, 0, stream>>>(qkvb, epos, scores, E_);
    attn_agg<<<(Mpad + 3) / 4, 256, 0, stream>>>(qkvb, rowp, epos, scores, aggb, N_, Mpad);

    // Wo GEMM + residual(x) + LN1 -> hb (bf16)
    mfma_gemm<128, 3><<<dim3(Mpad / 128, 1), 256, 0, stream>>>(
        aggb, WoT, bo, x, ln1g, ln1b, hb, N_, 128);

    // FF1: relu(h @ W1 + b1) -> tb (bf16)
    mfma_gemm<128, 1><<<dim3(Mpad / 128, 4), 256, 0, stream>>>(
        hb, W1T, b1, nullptr, nullptr, nullptr, tb, N_, 512);

    // FF2 + residual(hb) + LN2 -> out (f32)
    mfma_gemm<512, 4><<<dim3(Mpad / 128, 1), 256, 0, stream>>>(
        tb, W2T, b2, hb, ln2g, ln2b, out, N_, 128);
}

// Round 5
// 220.728 us; speedup vs baseline: 3.0517x; 1.2741x over previous
//
#include <hip/hip_runtime.h>
#include <math.h>

typedef __attribute__((ext_vector_type(8))) short bf16x8;
typedef __attribute__((ext_vector_type(4))) float f32x4;

__device__ __forceinline__ unsigned short f2b(float f) {
    unsigned int u = __float_as_uint(f);
    unsigned int r = (u + 0x7fffu + ((u >> 16) & 1u)) >> 16;   // RTNE
    return (unsigned short)r;
}
__device__ __forceinline__ float blo(unsigned int w) { return __uint_as_float(w << 16); }
__device__ __forceinline__ float bhi(unsigned int w) { return __uint_as_float(w & 0xffff0000u); }
__device__ __forceinline__ float b2f(unsigned short u) { return __uint_as_float((unsigned int)u << 16); }

__device__ __forceinline__ void gload_lds16(const void* g, void* lds) {
    __builtin_amdgcn_global_load_lds(
        (const __attribute__((address_space(1))) unsigned int*)g,
        (__attribute__((address_space(3))) unsigned int*)lds, 16, 0, 0);
}

// ---------------------------------------------------------------------------
// bf16 MFMA GEMM: out[M x NC] = epi(A[Mpad x K] @ W[K x NC] + bias)
// BT = W^T row-major [NC x K] bf16. Tile 128x128, BK=64, 4 waves, T2 swizzle.
// EPI: 1 = relu -> bf16 ws (unguarded, Mpad rows)
//      2 = bias -> bf16 ws (unguarded, Mpad rows)
//      3 = +res(f32) + LayerNorm -> bf16 ws (pad rows zeroed)   [NC==128]
//      4 = +res(bf16) + LayerNorm -> f32 out (guard row<M)      [NC==128]
// ---------------------------------------------------------------------------
template<int K, int EPI>
__global__ __launch_bounds__(256)
void mfma_gemm(const unsigned short* __restrict__ A,
               const unsigned short* __restrict__ BT,
               const float* __restrict__ bias,
               const void* __restrict__ res,
               const float* __restrict__ lng,
               const float* __restrict__ lnb,
               void* __restrict__ outv, int M, int NC)
{
    __shared__ unsigned short As[128 * 64];
    __shared__ unsigned short Bs[128 * 64];
    const int tid  = threadIdx.x;
    const int lane = tid & 63;
    const int wid  = tid >> 6;
    const int wr = wid >> 1, wc = wid & 1;
    const int rowBase = blockIdx.x * 128;
    const int colBase = blockIdx.y * 128;

    f32x4 acc[4][4];
#pragma unroll
    for (int i = 0; i < 4; ++i)
#pragma unroll
        for (int j = 0; j < 4; ++j) acc[i][j] = (f32x4)0.f;

    int srow[4], skoff[4];
#pragma unroll
    for (int t = 0; t < 4; ++t) {
        int c = tid + t * 256;
        int r = c >> 3, cc = c & 7;
        srow[t]  = r;
        skoff[t] = ((cc ^ (r & 7)) << 3);
    }

    const int rl = lane & 15;
    const int kh = lane >> 4;

    for (int k0 = 0; k0 < K; k0 += 64) {
#pragma unroll
        for (int t = 0; t < 4; ++t) {
            int c = tid + t * 256;
            gload_lds16(A + (size_t)(rowBase + srow[t]) * K + k0 + skoff[t], &As[c * 8]);
            gload_lds16(BT + (size_t)(colBase + srow[t]) * K + k0 + skoff[t], &Bs[c * 8]);
        }
        __syncthreads();

        bf16x8 a[4][2], b[4][2];
#pragma unroll
        for (int mi = 0; mi < 4; ++mi)
#pragma unroll
            for (int kt = 0; kt < 2; ++kt) {
                a[mi][kt] = *(const bf16x8*)&As[(((wr * 64 + mi * 16 + rl) * 64) + kt * 32 + kh * 8) ^ ((rl & 7) << 3)];
                b[mi][kt] = *(const bf16x8*)&Bs[(((wc * 64 + mi * 16 + rl) * 64) + kt * 32 + kh * 8) ^ ((rl & 7) << 3)];
            }
#pragma unroll
        for (int kt = 0; kt < 2; ++kt)
#pragma unroll
            for (int mi = 0; mi < 4; ++mi)
#pragma unroll
                for (int ni = 0; ni < 4; ++ni)
                    acc[mi][ni] = __builtin_amdgcn_mfma_f32_16x16x32_bf16(a[mi][kt], b[ni][kt], acc[mi][ni], 0, 0, 0);
        __syncthreads();
    }

    if (EPI == 3 || EPI == 4) {
        float* ls = (float*)As;
        float bb[4], gg[4], be[4];
#pragma unroll
        for (int ni = 0; ni < 4; ++ni) {
            int col = wc * 64 + ni * 16 + rl;
            bb[ni] = bias[col];
            gg[ni] = lng[col];
            be[ni] = lnb[col];
        }
#pragma unroll
        for (int mi = 0; mi < 4; ++mi) {
#pragma unroll
            for (int r = 0; r < 4; ++r) {
                int lrow = wr * 64 + mi * 16 + kh * 4 + r;
                int row  = rowBase + lrow;
                float s = 0.f, ss = 0.f;
#pragma unroll
                for (int ni = 0; ni < 4; ++ni) {
                    int col = wc * 64 + ni * 16 + rl;
                    float rr = 0.f;
                    if (row < M) {
                        if (EPI == 3) rr = ((const float*)res)[(size_t)row * 128 + col];
                        else          rr = b2f(((const unsigned short*)res)[(size_t)row * 128 + col]);
                    }
                    float v = acc[mi][ni][r] + bb[ni] + rr;
                    acc[mi][ni][r] = v;
                    s += v; ss += v * v;
                }
#pragma unroll
                for (int off = 1; off < 16; off <<= 1) {
                    s  += __shfl_xor(s,  off, 64);
                    ss += __shfl_xor(ss, off, 64);
                }
                if (rl == 0) {
                    ls[lrow * 2 + wc]       = s;
                    ls[256 + lrow * 2 + wc] = ss;
                }
            }
        }
        __syncthreads();
#pragma unroll
        for (int mi = 0; mi < 4; ++mi) {
#pragma unroll
            for (int r = 0; r < 4; ++r) {
                int lrow = wr * 64 + mi * 16 + kh * 4 + r;
                int row  = rowBase + lrow;
                float s  = ls[lrow * 2] + ls[lrow * 2 + 1];
                float ss = ls[256 + lrow * 2] + ls[256 + lrow * 2 + 1];
                float mean = s * (1.f / 128.f);
                float var  = ss * (1.f / 128.f) - mean * mean;
                float rstd = rsqrtf(var + 1e-5f);
#pragma unroll
                for (int ni = 0; ni < 4; ++ni) {
                    int col = wc * 64 + ni * 16 + rl;
                    float o = (acc[mi][ni][r] - mean) * rstd * gg[ni] + be[ni];
                    if (EPI == 3) {
                        ((unsigned short*)outv)[(size_t)row * 128 + col] = (row < M) ? f2b(o) : (unsigned short)0;
                    } else {
                        if (row < M) ((float*)outv)[(size_t)row * 128 + col] = o;
                    }
                }
            }
        }
    } else {
#pragma unroll
        for (int ni = 0; ni < 4; ++ni) {
            const int col = colBase + wc * 64 + ni * 16 + rl;
            const float bv = bias[col];
#pragma unroll
            for (int mi = 0; mi < 4; ++mi) {
                const int rowb = rowBase + wr * 64 + mi * 16 + kh * 4;
#pragma unroll
                for (int r = 0; r < 4; ++r) {
                    float v = acc[mi][ni][r] + bv;
                    if (EPI == 1) v = fmaxf(v, 0.f);
                    ((unsigned short*)outv)[(size_t)(rowb + r) * NC + col] = f2b(v);
                }
            }
        }
    }
}

// ---------------------------------------------------------------------------
// fused input casts: grid = xblocks (cast x) + 768 (cast/transpose weights)
// ---------------------------------------------------------------------------
__global__ void cast_all(const float* __restrict__ x, unsigned short* __restrict__ xb,
                         int n, int npad, int xblocks,
                         const float* __restrict__ Wq, const float* __restrict__ Wk,
                         const float* __restrict__ Wv, const float* __restrict__ Wo,
                         const float* __restrict__ W1, const float* __restrict__ W2,
                         const float* __restrict__ bq, const float* __restrict__ bk,
                         const float* __restrict__ bv,
                         unsigned short* __restrict__ WcatT, unsigned short* __restrict__ WoT,
                         unsigned short* __restrict__ W1T, unsigned short* __restrict__ W2T,
                         float* __restrict__ bqkv)
{
    if (blockIdx.x < (unsigned)xblocks) {
        size_t i = ((size_t)blockIdx.x * 256 + threadIdx.x) * 4;
        if (i >= (size_t)npad * 128) return;
        float4 v = make_float4(0.f, 0.f, 0.f, 0.f);
        if (i < (size_t)n * 128) v = *(const float4*)(x + i);
        ushort4 o;
        o.x = f2b(v.x); o.y = f2b(v.y); o.z = f2b(v.z); o.w = f2b(v.w);
        *(ushort4*)(xb + i) = o;
        return;
    }
    int i = (blockIdx.x - xblocks) * 256 + threadIdx.x;
    if (i < 49152) {
        int j = i >> 7, k = i & 127;
        const float* W = (j < 128) ? Wq : ((j < 256) ? Wk : Wv);
        WcatT[i] = f2b(W[k * 128 + (j & 127)]);
    } else if (i < 65536) {
        int t = i - 49152; int j = t >> 7, k = t & 127;
        WoT[t] = f2b(Wo[k * 128 + j]);
    } else if (i < 131072) {
        int t = i - 65536; int j = t >> 7, k = t & 127;
        W1T[t] = f2b(W1[k * 512 + j]);
    } else if (i < 196608) {
        int t = i - 131072; int j = t >> 9, k = t & 511;
        W2T[t] = f2b(W2[k * 128 + j]);
    }
    if (i < 384) bqkv[i] = (i < 128) ? bq[i] : ((i < 256) ? bk[i - 128] : bv[i - 256]);
}

// ---------------------------------------------------------------------------
// Bucketed counting sort of edges by target. Bucket = 64 consecutive targets
// (nb = ceil(n/64) <= 1024). Confines random writes within one workgroup so
// each 64B line is produced by one XCD -> L2 merges -> full-line writebacks.
// ---------------------------------------------------------------------------
#define EPB 8192   // edges per grouping block

__global__ __launch_bounds__(512)
void bucket_count(const int* __restrict__ tgt, int* __restrict__ bcnt, int E, int nb)
{
    __shared__ int hist[1024];
    int base = blockIdx.x * EPB;
    for (int i = threadIdx.x; i < nb; i += 512) hist[i] = 0;
    __syncthreads();
    int end = min(base + EPB, E);
    for (int e = base + threadIdx.x; e < end; e += 512)
        atomicAdd(&hist[tgt[e] >> 6], 1);
    __syncthreads();
    for (int i = threadIdx.x; i < nb; i += 512)
        if (hist[i] > 0) atomicAdd(&bcnt[i], hist[i]);
}

__global__ __launch_bounds__(64)
void bucket_scan(const int* __restrict__ bcnt, int* __restrict__ bstart,
                 int* __restrict__ bcur, int nb, int E)
{
    int lane = threadIdx.x;
    int carry = 0;
    for (int c = 0; c < nb; c += 64) {
        int idx = c + lane;
        int v = (idx < nb) ? bcnt[idx] : 0;
        int orig = v;
#pragma unroll
        for (int off = 1; off < 64; off <<= 1) {
            int y = __shfl_up(v, off, 64);
            if (lane >= off) v += y;
        }
        if (idx < nb) { int ex = carry + v - orig; bstart[idx] = ex; bcur[idx] = ex; }
        carry += __shfl(v, 63, 64);
    }
    if (lane == 0) bstart[nb] = E;
}

__global__ __launch_bounds__(512)
void bucket_group(const int* __restrict__ src, const int* __restrict__ tgt,
                  int* __restrict__ bcur, int2* __restrict__ stage, int E, int nb)
{
    __shared__ int2 eb[EPB];                       // 64 KB
    __shared__ int hist[1024], lofs[1024], lcur[1024], gbase[1024];
    int base = blockIdx.x * EPB;
    int tid = threadIdx.x;
    for (int i = tid; i < nb; i += 512) { hist[i] = 0; lcur[i] = 0; }
    __syncthreads();
    int end = min(base + EPB, E);
    for (int e = base + tid; e < end; e += 512)
        atomicAdd(&hist[tgt[e] >> 6], 1);
    __syncthreads();
    if (tid < 64) {
        int carry = 0;
        for (int c = 0; c < nb; c += 64) {
            int idx = c + tid;
            int v = (idx < nb) ? hist[idx] : 0;
            int orig = v;
#pragma unroll
            for (int off = 1; off < 64; off <<= 1) {
                int y = __shfl_up(v, off, 64);
                if (tid >= off) v += y;
            }
            if (idx < nb) lofs[idx] = carry + v - orig;
            carry += __shfl(v, 63, 64);
        }
    }
    __syncthreads();
    for (int e = base + tid; e < end; e += 512) {
        int t = tgt[e], b = t >> 6;
        int r = atomicAdd(&lcur[b], 1);
        eb[lofs[b] + r] = make_int2(src[e], t);
    }
    __syncthreads();
    for (int i = tid; i < nb; i += 512)
        if (hist[i] > 0) gbase[i] = atomicAdd(&bcur[i], hist[i]);
    __syncthreads();
    int cnt = end - base;
    for (int i = tid; i < cnt; i += 512) {
        int2 v = eb[i];
        int b = v.y >> 6;
        stage[gbase[b] + (i - lofs[b])] = v;
    }
}

// One block per bucket: local CSR over its 64 targets (writes rowp slice),
// LDS counting sort, coalesced epos write.
__global__ __launch_bounds__(256)
void bucket_sort(const int2* __restrict__ stage, const int* __restrict__ bstart,
                 int* __restrict__ rowp, int2* __restrict__ epos, int n, int nb)
{
    __shared__ int2 eb[3072], eb2[3072];           // 48 KB
    __shared__ int tcnt[64], tofs[64], tcur[64];
    int b = blockIdx.x;
    int t0 = b << 6;
    if (t0 >= n) return;
    int t1 = min(t0 + 64, n);
    int s0 = bstart[b], s1 = bstart[b + 1];
    int cnt = s1 - s0;
    int tid = threadIdx.x;
    if (tid < 64) { tcnt[tid] = 0; tcur[tid] = 0; }
    __syncthreads();
    bool fits = (cnt <= 3072);
    if (fits) {
        for (int i = tid; i < cnt; i += 256) {
            int2 v = stage[s0 + i];
            eb[i] = v;
            atomicAdd(&tcnt[v.y - t0], 1);
        }
    } else {
        for (int i = tid; i < cnt; i += 256)
            atomicAdd(&tcnt[stage[s0 + i].y - t0], 1);
    }
    __syncthreads();
    if (tid < 64) {
        int v = tcnt[tid], orig = v;
#pragma unroll
        for (int off = 1; off < 64; off <<= 1) {
            int y = __shfl_up(v, off, 64);
            if (tid >= off) v += y;
        }
        tofs[tid] = v - orig;                      // exclusive
        int t = t0 + tid;
        if (t < t1) rowp[t] = s0 + v - orig;
        if (t == n - 1) rowp[n] = s1;              // only last bucket's last target
    }
    __syncthreads();
    if (fits) {
        for (int i = tid; i < cnt; i += 256) {
            int2 v = eb[i];
            int lt = v.y - t0;
            int r = atomicAdd(&tcur[lt], 1);
            eb2[tofs[lt] + r] = v;
        }
        __syncthreads();
        for (int i = tid; i < cnt; i += 256) epos[s0 + i] = eb2[i];
    } else {
        for (int i = tid; i < cnt; i += 256) {
            int2 v = stage[s0 + i];
            int lt = v.y - t0;
            int r = atomicAdd(&tcur[lt], 1);
            epos[s0 + tofs[lt] + r] = v;           // block-exclusive region -> L2-merged
        }
    }
}

// ---------------------------------------------------------------------------
// Edge-parallel score kernel: 16 lanes per sorted edge.
// ---------------------------------------------------------------------------
#define SCORE_SCALE 0.360673760222241f   // 0.25 * log2(e)

__global__ __launch_bounds__(256)
void score_kernel(const unsigned short* __restrict__ qkv, const int2* __restrict__ epos,
                  float* __restrict__ scores, int E)
{
    int gw = (blockIdx.x * 256 + threadIdx.x) >> 4;
    int el = threadIdx.x & 15;
    if (gw >= E) return;
    int2 st = epos[gw];
    uint4 qv = *(const uint4*)(qkv + (size_t)st.y * 384 + el * 8);
    uint4 kv = *(const uint4*)(qkv + (size_t)st.x * 384 + 128 + el * 8);
    float d;
    d  = blo(qv.x) * blo(kv.x) + bhi(qv.x) * bhi(kv.x);
    d += blo(qv.y) * blo(kv.y) + bhi(qv.y) * bhi(kv.y);
    d += blo(qv.z) * blo(kv.z) + bhi(qv.z) * bhi(kv.z);
    d += blo(qv.w) * blo(kv.w) + bhi(qv.w) * bhi(kv.w);
    d += __shfl_xor(d, 1, 64);
    if ((el & 1) == 0)
        scores[(size_t)gw * 8 + (el >> 1)] = d * SCORE_SCALE;
}

// ---------------------------------------------------------------------------
// Aggregation: wave per target node, online softmax (base 2), 4-edge unroll.
// ---------------------------------------------------------------------------
__global__ __launch_bounds__(256)
void attn_agg(const unsigned short* __restrict__ qkv, const int* __restrict__ rowp,
              const int2* __restrict__ epos, const float* __restrict__ scores,
              unsigned short* __restrict__ agg, int n, int npad)
{
    int wid  = (blockIdx.x * blockDim.x + threadIdx.x) >> 6;
    int lane = threadIdx.x & 63;
    if (wid >= npad) return;
    if (wid >= n) { *(unsigned int*)(agg + (size_t)wid * 128 + lane * 2) = 0u; return; }

    const int head = lane >> 3;
    int e = rowp[wid];
    const int e1 = rowp[wid + 1];

    float m = -INFINITY, l = 0.f, a0 = 0.f, a1 = 0.f;

    for (; e + 4 <= e1; e += 4) {
        int s0 = epos[e].x, s1 = epos[e + 1].x, s2 = epos[e + 2].x, s3 = epos[e + 3].x;
        float sc0 = scores[(size_t)e * 8 + head];
        float sc1 = scores[(size_t)(e + 1) * 8 + head];
        float sc2 = scores[(size_t)(e + 2) * 8 + head];
        float sc3 = scores[(size_t)(e + 3) * 8 + head];
        unsigned int v0 = *(const unsigned int*)(qkv + (size_t)s0 * 384 + 256 + lane * 2);
        unsigned int v1 = *(const unsigned int*)(qkv + (size_t)s1 * 384 + 256 + lane * 2);
        unsigned int v2 = *(const unsigned int*)(qkv + (size_t)s2 * 384 + 256 + lane * 2);
        unsigned int v3 = *(const unsigned int*)(qkv + (size_t)s3 * 384 + 256 + lane * 2);
        float mn = fmaxf(fmaxf(fmaxf(sc0, sc1), fmaxf(sc2, sc3)), m);
        float scale = exp2f(m - mn);
        float w0 = exp2f(sc0 - mn), w1 = exp2f(sc1 - mn);
        float w2 = exp2f(sc2 - mn), w3 = exp2f(sc3 - mn);
        l  = l * scale + ((w0 + w1) + (w2 + w3));
        a0 = a0 * scale + (w0 * blo(v0) + w1 * blo(v1)) + (w2 * blo(v2) + w3 * blo(v3));
        a1 = a1 * scale + (w0 * bhi(v0) + w1 * bhi(v1)) + (w2 * bhi(v2) + w3 * bhi(v3));
        m = mn;
    }
    for (; e < e1; ++e) {
        int s = epos[e].x;
        float sc = scores[(size_t)e * 8 + head];
        unsigned int vw = *(const unsigned int*)(qkv + (size_t)s * 384 + 256 + lane * 2);
        float mn = fmaxf(m, sc);
        float scale = exp2f(m - mn);
        float w = exp2f(sc - mn);
        l  = l * scale + w;
        a0 = a0 * scale + w * blo(vw);
        a1 = a1 * scale + w * bhi(vw);
        m = mn;
    }
    float inv = 1.f / (l + 1e-16f);
    unsigned int o = (unsigned int)f2b(a0 * inv) | ((unsigned int)f2b(a1 * inv) << 16);
    *(unsigned int*)(agg + (size_t)wid * 128 + lane * 2) = o;
}

// ---------------------------------------------------------------------------
extern "C" void kernel_launch(void* const* d_in, const int* in_sizes, int n_in,
                              void* d_out, int out_size, void* d_ws, size_t ws_size,
                              hipStream_t stream)
{
    const float* x    = (const float*)d_in[0];
    const float* Wq   = (const float*)d_in[1];
    const float* bq   = (const float*)d_in[2];
    const float* Wk   = (const float*)d_in[3];
    const float* bk   = (const float*)d_in[4];
    const float* Wv   = (const float*)d_in[5];
    const float* bv   = (const float*)d_in[6];
    const float* Wo   = (const float*)d_in[7];
    const float* bo   = (const float*)d_in[8];
    const float* ln1g = (const float*)d_in[9];
    const float* ln1b = (const float*)d_in[10];
    const float* W1   = (const float*)d_in[11];
    const float* b1   = (const float*)d_in[12];
    const float* W2   = (const float*)d_in[13];
    const float* b2   = (const float*)d_in[14];
    const float* ln2g = (const float*)d_in[15];
    const float* ln2b = (const float*)d_in[16];
    const int*   eidx = (const int*)d_in[17];

    const int N_ = in_sizes[0] / 128;
    const int E_ = in_sizes[17] / 2;
    const int Mpad = ((N_ + 127) / 128) * 128;
    const int nb = (N_ + 63) >> 6;                 // buckets of 64 targets (<=1024)
    const int* srcE = eidx;
    const int* tgtE = eidx + E_;
    float* out = (float*)d_out;

    // workspace layout
    unsigned short* xb   = (unsigned short*)d_ws;                 // [Mpad][128]
    unsigned short* qkvb = xb + (size_t)Mpad * 128;               // [Mpad][384]
    unsigned short* tb   = xb;                                    // alias [Mpad][512]
    unsigned short* aggb = qkvb + (size_t)Mpad * 384;             // [Mpad][128]
    unsigned short* hb   = aggb + (size_t)Mpad * 128;             // [Mpad][128]
    float* scores        = (float*)(hb + (size_t)Mpad * 128);     // [E][8] f32
    unsigned short* WcatT = (unsigned short*)(scores + (size_t)E_ * 8);
    unsigned short* WoT  = WcatT + 384 * 128;
    unsigned short* W1T  = WoT + 128 * 128;
    unsigned short* W2T  = W1T + 512 * 128;
    float* bqkv          = (float*)(W2T + 128 * 512);
    int2* stage          = (int2*)(bqkv + 384);                   // [E]
    int2* epos           = stage + E_;                            // [E]
    int* bcnt   = (int*)(epos + E_);                              // [1024]
    int* bstart = bcnt + 1024;                                    // [1025]
    int* bcur   = bstart + 1025;                                  // [1024]
    int* rowp   = bcur + 1024;                                    // [N+1]

    hipMemsetAsync(bcnt, 0, sizeof(int) * 1024, stream);

    const int xblocks = (int)(((size_t)Mpad * 128 / 4 + 255) / 256);
    const int gblocks = (E_ + EPB - 1) / EPB;

    cast_all<<<xblocks + 768, 256, 0, stream>>>(x, xb, N_, Mpad, xblocks,
                                                Wq, Wk, Wv, Wo, W1, W2, bq, bk, bv,
                                                WcatT, WoT, W1T, W2T, bqkv);

    // QKV fused GEMM: [Mpad x 128] @ [128 x 384]
    mfma_gemm<128, 2><<<dim3(Mpad / 128, 3), 256, 0, stream>>>(
        xb, WcatT, bqkv, nullptr, nullptr, nullptr, qkvb, N_, 384);

    // edge sort by target
    bucket_count<<<gblocks, 512, 0, stream>>>(tgtE, bcnt, E_, nb);
    bucket_scan<<<1, 64, 0, stream>>>(bcnt, bstart, bcur, nb, E_);
    bucket_group<<<gblocks, 512, 0, stream>>>(srcE, tgtE, bcur, stage, E_, nb);
    bucket_sort<<<nb, 256, 0, stream>>>(stage, bstart, rowp, epos, N_, nb);

    score_kernel<<<((size_t)E_ * 16 + 255) / 256, 256, 0, stream>>>(qkvb, epos, scores, E_);
    attn_agg<<<(Mpad + 3) / 4, 256, 0, stream>>>(qkvb, rowp, epos, scores, aggb, N_, Mpad);

    // Wo GEMM + residual(x) + LN1 -> hb (bf16)
    mfma_gemm<128, 3><<<dim3(Mpad / 128, 1), 256, 0, stream>>>(
        aggb, WoT, bo, x, ln1g, ln1b, hb, N_, 128);

    // FF1: relu(h @ W1 + b1) -> tb (bf16)
    mfma_gemm<128, 1><<<dim3(Mpad / 128, 4), 256, 0, stream>>>(
        hb, W1T, b1, nullptr, nullptr, nullptr, tb, N_, 512);

    // FF2 + residual(hb) + LN2 -> out (f32)
    mfma_gemm<512, 4><<<dim3(Mpad / 128, 1), 256, 0, stream>>>(
        tb, W2T, b2, hb, ln2g, ln2b, out, N_, 128);
}